// Round 5
// baseline (766.197 us; speedup 1.0000x reference)
//
#include <hip/hip_runtime.h>

#define N_NODES 100000
#define N_EDGES 1600000
#define N_GRAPHS 1024
#define F_IN 128
#define HDIM 64
#define NCOARSE 391          // ceil(100000 / 256) dst>>8 buckets
#define NSEG (NCOARSE * 8)   // 8 xcd-group segments per bucket
#define NBLK_AB 1024
#define EPB 1563             // ceil(N_EDGES / NBLK_AB)

// ---------------------------------------------------------------------------
__global__ void zero_k(int* __restrict__ ccnt8, float* __restrict__ gsum,
                       float* __restrict__ gcnt) {
    int i = blockIdx.x * blockDim.x + threadIdx.x;
    int stride = gridDim.x * blockDim.x;
    for (int j = i; j < NSEG; j += stride) ccnt8[j] = 0;
    for (int j = i; j < N_GRAPHS; j += stride) { gsum[j] = 0.0f; gcnt[j] = 0.0f; }
}

// per-block LDS coarse histogram; merge into per-(bucket, blockIdx&7) counters
__global__ __launch_bounds__(256) void coarse_hist_k(const int* __restrict__ dst,
                                                     int* __restrict__ ccnt8) {
    __shared__ int hist[NCOARSE];
    for (int i = threadIdx.x; i < NCOARSE; i += 256) hist[i] = 0;
    __syncthreads();
    int b = blockIdx.x;
    int e0 = b * EPB, e1 = min(e0 + EPB, N_EDGES);
    for (int e = e0 + threadIdx.x; e < e1; e += 256)
        atomicAdd(&hist[dst[e] >> 8], 1);
    __syncthreads();
    int x = b & 7;
    for (int c = threadIdx.x; c < NCOARSE; c += 256) {
        int v = hist[c];
        if (v) atomicAdd(&ccnt8[c * 8 + x], v);
    }
}

// exclusive scan of the 3128 segment counts (layout: bucket-major, xcd minor)
__global__ __launch_bounds__(1024) void coarse_scan_k(const int* __restrict__ ccnt8,
                                                      int* __restrict__ coffs,
                                                      int* __restrict__ ccur8) {
    __shared__ int tsum[1024];
    int t = threadIdx.x;
    int base = t * 4;
    int v[4], s = 0;
#pragma unroll
    for (int j = 0; j < 4; ++j) {
        int idx = base + j;
        v[j] = (idx < NSEG) ? ccnt8[idx] : 0;
        s += v[j];
    }
    tsum[t] = s;
    __syncthreads();
    for (int o = 1; o < 1024; o <<= 1) {
        int add = (t >= o) ? tsum[t - o] : 0;
        __syncthreads();
        tsum[t] += add;
        __syncthreads();
    }
    int excl = tsum[t] - s;
#pragma unroll
    for (int j = 0; j < 4; ++j) {
        int idx = base + j;
        if (idx < NSEG) { coffs[idx] = excl; ccur8[idx] = excl; }
        excl += v[j];
    }
    if (t == 1023) coffs[NSEG] = tsum[1023];
}

// coarse scatter: 4B code (src | dstoff<<17) into per-(bucket,xcd-group) stream
__global__ __launch_bounds__(256) void coarse_scatter_k(const int* __restrict__ src,
                                                        const int* __restrict__ dst,
                                                        int* __restrict__ ccur8,
                                                        int* __restrict__ eC) {
    int b = blockIdx.x, x = b & 7;
    int e0 = b * EPB, e1 = min(e0 + EPB, N_EDGES);
    for (int e = e0 + threadIdx.x; e < e1; e += 256) {
        int s = src[e], d = dst[e];
        int pos = atomicAdd(&ccur8[(d >> 8) * 8 + x], 1);
        eC[pos] = s | ((d & 255) << 17);
    }
}

// per bucket: node counts (LDS) -> rowptr + dinv (replaces global hist/dinv/scan)
__global__ __launch_bounds__(256) void bucket_count_k(const int* __restrict__ eC,
                                                      const int* __restrict__ coffs,
                                                      int* __restrict__ rowptr,
                                                      float* __restrict__ dinv) {
    __shared__ int cnt[256];
    __shared__ int sc[256];
    int c = blockIdx.x, t = threadIdx.x;
    cnt[t] = 0;
    __syncthreads();
    int s0 = coffs[c * 8], s1 = coffs[c * 8 + 8];  // bucket's 8 segs are adjacent
    for (int e = s0 + t; e < s1; e += 256)
        atomicAdd(&cnt[(eC[e] >> 17) & 255], 1);
    __syncthreads();
    int v = cnt[t];
    sc[t] = v;
    __syncthreads();
    for (int o = 1; o < 256; o <<= 1) {
        int add = (t >= o) ? sc[t - o] : 0;
        __syncthreads();
        sc[t] += add;
        __syncthreads();
    }
    int node = c * 256 + t;
    if (node < N_NODES) {
        rowptr[node] = s0 + sc[t] - v;
        dinv[node] = rsqrtf((float)v + 1.0f);  // +1 self loop
    }
    if (node == N_NODES - 1) rowptr[N_NODES] = s1;
}

// per bucket: final scatter with norm; writes land in a block-exclusive region
__global__ __launch_bounds__(256) void bucket_scatter_k(const int* __restrict__ eC,
                                                        const int* __restrict__ coffs,
                                                        const int* __restrict__ rowptr,
                                                        const float* __restrict__ dinv,
                                                        int2* __restrict__ epack) {
    __shared__ int cur[256];
    __shared__ float dv[256];
    int c = blockIdx.x, t = threadIdx.x;
    int node = c * 256 + t;
    cur[t] = (node < N_NODES) ? rowptr[node] : 0;
    dv[t] = (node < N_NODES) ? dinv[node] : 0.0f;
    __syncthreads();
    int s0 = coffs[c * 8], s1 = coffs[c * 8 + 8];
    for (int e = s0 + t; e < s1; e += 256) {
        int u = eC[e];
        int s = u & 0x1FFFF;
        int doff = (u >> 17) & 255;
        float nm = dinv[s] * dv[doff];
        int pos = atomicAdd(&cur[doff], 1);
        epack[pos] = make_int2(s, __float_as_int(nm));
    }
}

// ---------------------------------------------------------------------------
// Register-blocked GEMM, no LDS. 1563 blocks x 64 rows; thread: 2 rows x 8 cols.
#define FMA8(av, wl, wh, accrow)                       \
    accrow[0] = fmaf(av, wl.x, accrow[0]);             \
    accrow[1] = fmaf(av, wl.y, accrow[1]);             \
    accrow[2] = fmaf(av, wl.z, accrow[2]);             \
    accrow[3] = fmaf(av, wl.w, accrow[3]);             \
    accrow[4] = fmaf(av, wh.x, accrow[4]);             \
    accrow[5] = fmaf(av, wh.y, accrow[5]);             \
    accrow[6] = fmaf(av, wh.z, accrow[6]);             \
    accrow[7] = fmaf(av, wh.w, accrow[7]);

template <int K>
__global__ __launch_bounds__(256) void gemm_k(const float* __restrict__ A,
                                              const float* __restrict__ W,
                                              float* __restrict__ out) {
    const int tx = threadIdx.x & 7;
    const int ty = threadIdx.x >> 3;   // 0..31
    const int c0 = tx * 8;
    const int r0 = blockIdx.x * 64 + ty * 2;
    float acc[2][8];
#pragma unroll
    for (int i = 0; i < 2; ++i)
#pragma unroll
        for (int j = 0; j < 8; ++j) acc[i][j] = 0.0f;

#pragma unroll 2
    for (int kc = 0; kc < K; kc += 4) {
        float4 a[2];
#pragma unroll
        for (int i = 0; i < 2; ++i) {
            int r = r0 + i;
            a[i] = (r < N_NODES) ? *(const float4*)(A + (size_t)r * K + kc)
                                 : make_float4(0.f, 0.f, 0.f, 0.f);
        }
        float4 wlo[4], whi[4];
#pragma unroll
        for (int j = 0; j < 4; ++j) {
            wlo[j] = *(const float4*)(W + (size_t)(kc + j) * HDIM + c0);
            whi[j] = *(const float4*)(W + (size_t)(kc + j) * HDIM + c0 + 4);
        }
#pragma unroll
        for (int i = 0; i < 2; ++i) {
            FMA8(a[i].x, wlo[0], whi[0], acc[i]);
            FMA8(a[i].y, wlo[1], whi[1], acc[i]);
            FMA8(a[i].z, wlo[2], whi[2], acc[i]);
            FMA8(a[i].w, wlo[3], whi[3], acc[i]);
        }
    }
#pragma unroll
    for (int i = 0; i < 2; ++i) {
        int r = r0 + i;
        if (r < N_NODES) {
            float4 lo = make_float4(acc[i][0], acc[i][1], acc[i][2], acc[i][3]);
            float4 hi = make_float4(acc[i][4], acc[i][5], acc[i][6], acc[i][7]);
            *(float4*)(out + (size_t)r * HDIM + c0) = lo;
            *(float4*)(out + (size_t)r * HDIM + c0 + 4) = hi;
        }
    }
}

// ---------------------------------------------------------------------------
// one wave per dst node; wave-uniform int4 metadata loads, 8 gathers in flight.
template <bool RELU_OUT>
__global__ __launch_bounds__(256) void agg_k(const int* __restrict__ rowptr,
                                             const int2* __restrict__ epack,
                                             const float* __restrict__ dinv,
                                             const float* __restrict__ hw,
                                             const float* __restrict__ b,
                                             float* __restrict__ h) {
    const int lane = threadIdx.x & 63;
    int node = (blockIdx.x * 256 + threadIdx.x) >> 6;
    if (node >= N_NODES) return;
    int e0 = rowptr[node], e1 = rowptr[node + 1];
    float dv = dinv[node];
    float acc = b[lane] + hw[(size_t)node * HDIM + lane] * dv * dv;

    int e = e0;
    if ((e & 1) && e < e1) {
        int2 m = epack[e];
        acc = fmaf(hw[(size_t)m.x * HDIM + lane], __int_as_float(m.y), acc);
        ++e;
    }
    for (; e + 8 <= e1; e += 8) {
        int4 m0 = *(const int4*)(epack + e);
        int4 m1 = *(const int4*)(epack + e + 2);
        int4 m2 = *(const int4*)(epack + e + 4);
        int4 m3 = *(const int4*)(epack + e + 6);
        float v0 = hw[(size_t)m0.x * HDIM + lane];
        float v1 = hw[(size_t)m0.z * HDIM + lane];
        float v2 = hw[(size_t)m1.x * HDIM + lane];
        float v3 = hw[(size_t)m1.z * HDIM + lane];
        float v4 = hw[(size_t)m2.x * HDIM + lane];
        float v5 = hw[(size_t)m2.z * HDIM + lane];
        float v6 = hw[(size_t)m3.x * HDIM + lane];
        float v7 = hw[(size_t)m3.z * HDIM + lane];
        acc = fmaf(v0, __int_as_float(m0.y), acc);
        acc = fmaf(v1, __int_as_float(m0.w), acc);
        acc = fmaf(v2, __int_as_float(m1.y), acc);
        acc = fmaf(v3, __int_as_float(m1.w), acc);
        acc = fmaf(v4, __int_as_float(m2.y), acc);
        acc = fmaf(v5, __int_as_float(m2.w), acc);
        acc = fmaf(v6, __int_as_float(m3.y), acc);
        acc = fmaf(v7, __int_as_float(m3.w), acc);
    }
    for (; e < e1; ++e) {
        int2 m = epack[e];
        acc = fmaf(hw[(size_t)m.x * HDIM + lane], __int_as_float(m.y), acc);
    }
    if (RELU_OUT) acc = fmaxf(acc, 0.0f);
    h[(size_t)node * HDIM + lane] = acc;
}

// ---------------------------------------------------------------------------
__global__ __launch_bounds__(256) void pool_k(const float* __restrict__ h,
                                              const int* __restrict__ batch,
                                              const float* __restrict__ lw,
                                              float* __restrict__ gsum,
                                              float* __restrict__ gcnt) {
    int i = blockIdx.x * blockDim.x + threadIdx.x;
    bool act = i < N_NODES;
    float dot = 0.0f;
    int g = -1;
    if (act) {
        g = batch[i];
        const float4* row = (const float4*)(h + (size_t)i * HDIM);
        const float4* w4  = (const float4*)lw;
#pragma unroll
        for (int q = 0; q < 16; ++q) {
            float4 v = row[q], w = w4[q];
            dot = fmaf(v.x, w.x, dot);
            dot = fmaf(v.y, w.y, dot);
            dot = fmaf(v.z, w.z, dot);
            dot = fmaf(v.w, w.w, dot);
        }
    }
    int g0 = __shfl(g, 0);
    bool uni = (__ballot(act && (g == g0)) == ~0ULL);
    if (uni) {
        for (int o = 32; o > 0; o >>= 1) dot += __shfl_down(dot, o);
        if ((threadIdx.x & 63) == 0) {
            atomicAdd(&gsum[g0], dot);
            atomicAdd(&gcnt[g0], 64.0f);
        }
    } else if (act) {
        atomicAdd(&gsum[g], dot);
        atomicAdd(&gcnt[g], 1.0f);
    }
}

__global__ void final_k(float* __restrict__ out, const float* __restrict__ gsum,
                        const float* __restrict__ gcnt, const float* __restrict__ lb) {
    int g = blockIdx.x * blockDim.x + threadIdx.x;
    if (g < N_GRAPHS) out[g] = gsum[g] / fmaxf(gcnt[g], 1.0f) + lb[0];
}

// ---------------------------------------------------------------------------
extern "C" void kernel_launch(void* const* d_in, const int* in_sizes, int n_in,
                              void* d_out, int out_size, void* d_ws, size_t ws_size,
                              hipStream_t stream) {
    const float* x     = (const float*)d_in[0];
    const int*   eidx  = (const int*)d_in[1];   // [2, E] int32
    const int*   batch = (const int*)d_in[3];
    const float* W1 = (const float*)d_in[4];
    const float* b1 = (const float*)d_in[5];
    const float* W2 = (const float*)d_in[6];
    const float* b2 = (const float*)d_in[7];
    const float* W3 = (const float*)d_in[8];
    const float* b3 = (const float*)d_in[9];
    const float* lin_w = (const float*)d_in[10];
    const float* lin_b = (const float*)d_in[11];
    float* out = (float*)d_out;

    const int* src = eidx;
    const int* dst = eidx + N_EDGES;

    float* ws     = (float*)d_ws;
    float* dinv   = ws;                         // 100352 f
    int*   rowptr = (int*)(ws + 100352);        // 100352 i (needs 100001)
    int*   ccnt8  = rowptr + 100352;            // 3200
    int*   coffs  = ccnt8 + 3200;               // 3200 (needs NSEG+1)
    int*   ccur8  = coffs + 3200;               // 3200
    int2*  epack  = (int2*)(ccur8 + 3200);      // 1.6M int2, 16B-aligned
    float* bufA   = (float*)(epack + N_EDGES);  // 6.4M f
    float* bufB   = bufA + 6400000;             // 6.4M f
    float* gsum   = bufB + 6400000;             // 1024
    float* gcnt   = gsum + 1024;                // 1024   (~65 MB total)
    int*   eC     = (int*)bufA;                 // 1.6M i, aliases bufA (dead before gemm1)

    // ---- CSR build (once; reused by all 3 layers) ----
    zero_k<<<64, 256, 0, stream>>>(ccnt8, gsum, gcnt);
    coarse_hist_k<<<NBLK_AB, 256, 0, stream>>>(dst, ccnt8);
    coarse_scan_k<<<1, 1024, 0, stream>>>(ccnt8, coffs, ccur8);
    coarse_scatter_k<<<NBLK_AB, 256, 0, stream>>>(src, dst, ccur8, eC);
    bucket_count_k<<<NCOARSE, 256, 0, stream>>>(eC, coffs, rowptr, dinv);
    bucket_scatter_k<<<NCOARSE, 256, 0, stream>>>(eC, coffs, rowptr, dinv, epack);

    // ---- 3 GCN layers (relu folded into agg store) ----
    gemm_k<F_IN><<<1563, 256, 0, stream>>>(x, W1, bufA);
    agg_k<true><<<25000, 256, 0, stream>>>(rowptr, epack, dinv, bufA, b1, bufB);

    gemm_k<HDIM><<<1563, 256, 0, stream>>>(bufB, W2, bufA);
    agg_k<true><<<25000, 256, 0, stream>>>(rowptr, epack, dinv, bufA, b2, bufB);

    gemm_k<HDIM><<<1563, 256, 0, stream>>>(bufB, W3, bufA);
    agg_k<false><<<25000, 256, 0, stream>>>(rowptr, epack, dinv, bufA, b3, bufB);

    // ---- pool + head ----
    pool_k<<<(N_NODES + 255) / 256, 256, 0, stream>>>(bufB, batch, lin_w, gsum, gcnt);
    final_k<<<(N_GRAPHS + 255) / 256, 256, 0, stream>>>(out, gsum, gcnt, lin_b);
}

// Round 6
// 711.810 us; speedup vs baseline: 1.0764x; 1.0764x over previous
//
#include <hip/hip_runtime.h>

#define N_NODES 100000
#define N_EDGES 1600000
#define N_GRAPHS 1024
#define F_IN 128
#define HDIM 64
#define NCOARSE 391          // ceil(100000 / 256) dst>>8 buckets
#define XS 32                // segments per bucket (blockIdx & 31)
#define PAD 16               // ints per counter -> one 64B line each
#define NSEGX (NCOARSE * XS) // 12512
#define SPT 13               // scan elements per thread (13*1024 >= 12512+1)
#define NBLK_AB 1024
#define EPB 1563             // ceil(N_EDGES / NBLK_AB)

// ---------------------------------------------------------------------------
__global__ void zero_k(int* __restrict__ ccntp, float* __restrict__ gsum,
                       float* __restrict__ gcnt) {
    int i = blockIdx.x * blockDim.x + threadIdx.x;
    int stride = gridDim.x * blockDim.x;
    for (int j = i; j < NSEGX * PAD; j += stride) ccntp[j] = 0;
    for (int j = i; j < N_GRAPHS; j += stride) { gsum[j] = 0.0f; gcnt[j] = 0.0f; }
}

// per-block LDS coarse histogram; merge into padded per-(bucket,seg) counters
__global__ __launch_bounds__(256) void coarse_hist_k(const int* __restrict__ dst,
                                                     int* __restrict__ ccntp) {
    __shared__ int hist[NCOARSE];
    for (int i = threadIdx.x; i < NCOARSE; i += 256) hist[i] = 0;
    __syncthreads();
    int b = blockIdx.x;
    int e0 = b * EPB, e1 = min(e0 + EPB, N_EDGES);
    for (int e = e0 + threadIdx.x; e < e1; e += 256)
        atomicAdd(&hist[dst[e] >> 8], 1);
    __syncthreads();
    int x = b & (XS - 1);
    for (int c = threadIdx.x; c < NCOARSE; c += 256) {
        int v = hist[c];
        if (v) atomicAdd(&ccntp[(c * XS + x) * PAD], v);
    }
}

// exclusive scan of 12512 padded segment counts -> coffs (compact) + ccurp (padded)
__global__ __launch_bounds__(1024) void coarse_scan_k(const int* __restrict__ ccntp,
                                                      int* __restrict__ coffs,
                                                      int* __restrict__ ccurp) {
    __shared__ int tsum[1024];
    int t = threadIdx.x;
    int s = 0;
    for (int j = 0; j < SPT; ++j) {
        int idx = t * SPT + j;
        if (idx < NSEGX) s += ccntp[idx * PAD];
    }
    tsum[t] = s;
    __syncthreads();
    for (int o = 1; o < 1024; o <<= 1) {
        int add = (t >= o) ? tsum[t - o] : 0;
        __syncthreads();
        tsum[t] += add;
        __syncthreads();
    }
    int excl = tsum[t] - s;
    for (int j = 0; j < SPT; ++j) {
        int idx = t * SPT + j;
        if (idx < NSEGX) {
            int v = ccntp[idx * PAD];
            coffs[idx] = excl;
            ccurp[idx * PAD] = excl;
            excl += v;
        }
    }
    if (t == 1023) coffs[NSEGX] = tsum[1023];
}

// coarse scatter: 4B code (src | dstoff<<17) via padded line-exclusive cursors
__global__ __launch_bounds__(256) void coarse_scatter_k(const int* __restrict__ src,
                                                        const int* __restrict__ dst,
                                                        int* __restrict__ ccurp,
                                                        int* __restrict__ eC) {
    int b = blockIdx.x, x = b & (XS - 1);
    int e0 = b * EPB, e1 = min(e0 + EPB, N_EDGES);
    for (int e = e0 + threadIdx.x; e < e1; e += 256) {
        int s = src[e], d = dst[e];
        int pos = atomicAdd(&ccurp[((d >> 8) * XS + x) * PAD], 1);
        eC[pos] = s | ((d & 255) << 17);
    }
}

// per bucket: node counts (LDS) -> rowptr + dinv
__global__ __launch_bounds__(256) void bucket_count_k(const int* __restrict__ eC,
                                                      const int* __restrict__ coffs,
                                                      int* __restrict__ rowptr,
                                                      float* __restrict__ dinv) {
    __shared__ int cnt[256];
    __shared__ int sc[256];
    int c = blockIdx.x, t = threadIdx.x;
    cnt[t] = 0;
    __syncthreads();
    int s0 = coffs[c * XS], s1 = coffs[c * XS + XS];  // bucket's segs adjacent
    for (int e = s0 + t; e < s1; e += 256)
        atomicAdd(&cnt[(eC[e] >> 17) & 255], 1);
    __syncthreads();
    int v = cnt[t];
    sc[t] = v;
    __syncthreads();
    for (int o = 1; o < 256; o <<= 1) {
        int add = (t >= o) ? sc[t - o] : 0;
        __syncthreads();
        sc[t] += add;
        __syncthreads();
    }
    int node = c * 256 + t;
    if (node < N_NODES) {
        rowptr[node] = s0 + sc[t] - v;
        dinv[node] = rsqrtf((float)v + 1.0f);  // +1 self loop
    }
    if (node == N_NODES - 1) rowptr[N_NODES] = s1;
}

// per bucket: final scatter with norm; writes land in a block-exclusive region
__global__ __launch_bounds__(256) void bucket_scatter_k(const int* __restrict__ eC,
                                                        const int* __restrict__ coffs,
                                                        const int* __restrict__ rowptr,
                                                        const float* __restrict__ dinv,
                                                        int2* __restrict__ epack) {
    __shared__ int cur[256];
    __shared__ float dv[256];
    int c = blockIdx.x, t = threadIdx.x;
    int node = c * 256 + t;
    cur[t] = (node < N_NODES) ? rowptr[node] : 0;
    dv[t] = (node < N_NODES) ? dinv[node] : 0.0f;
    __syncthreads();
    int s0 = coffs[c * XS], s1 = coffs[c * XS + XS];
    for (int e = s0 + t; e < s1; e += 256) {
        int u = eC[e];
        int s = u & 0x1FFFF;
        int doff = (u >> 17) & 255;
        float nm = dinv[s] * dv[doff];
        int pos = atomicAdd(&cur[doff], 1);
        epack[pos] = make_int2(s, __float_as_int(nm));
    }
}

// ---------------------------------------------------------------------------
// Register-blocked GEMM, no LDS. 1563 blocks x 64 rows; thread: 2 rows x 8 cols.
#define FMA8(av, wl, wh, accrow)                       \
    accrow[0] = fmaf(av, wl.x, accrow[0]);             \
    accrow[1] = fmaf(av, wl.y, accrow[1]);             \
    accrow[2] = fmaf(av, wl.z, accrow[2]);             \
    accrow[3] = fmaf(av, wl.w, accrow[3]);             \
    accrow[4] = fmaf(av, wh.x, accrow[4]);             \
    accrow[5] = fmaf(av, wh.y, accrow[5]);             \
    accrow[6] = fmaf(av, wh.z, accrow[6]);             \
    accrow[7] = fmaf(av, wh.w, accrow[7]);

template <int K>
__global__ __launch_bounds__(256) void gemm_k(const float* __restrict__ A,
                                              const float* __restrict__ W,
                                              float* __restrict__ out) {
    const int tx = threadIdx.x & 7;
    const int ty = threadIdx.x >> 3;   // 0..31
    const int c0 = tx * 8;
    const int r0 = blockIdx.x * 64 + ty * 2;
    float acc[2][8];
#pragma unroll
    for (int i = 0; i < 2; ++i)
#pragma unroll
        for (int j = 0; j < 8; ++j) acc[i][j] = 0.0f;

#pragma unroll 2
    for (int kc = 0; kc < K; kc += 4) {
        float4 a[2];
#pragma unroll
        for (int i = 0; i < 2; ++i) {
            int r = r0 + i;
            a[i] = (r < N_NODES) ? *(const float4*)(A + (size_t)r * K + kc)
                                 : make_float4(0.f, 0.f, 0.f, 0.f);
        }
        float4 wlo[4], whi[4];
#pragma unroll
        for (int j = 0; j < 4; ++j) {
            wlo[j] = *(const float4*)(W + (size_t)(kc + j) * HDIM + c0);
            whi[j] = *(const float4*)(W + (size_t)(kc + j) * HDIM + c0 + 4);
        }
#pragma unroll
        for (int i = 0; i < 2; ++i) {
            FMA8(a[i].x, wlo[0], whi[0], acc[i]);
            FMA8(a[i].y, wlo[1], whi[1], acc[i]);
            FMA8(a[i].z, wlo[2], whi[2], acc[i]);
            FMA8(a[i].w, wlo[3], whi[3], acc[i]);
        }
    }
#pragma unroll
    for (int i = 0; i < 2; ++i) {
        int r = r0 + i;
        if (r < N_NODES) {
            float4 lo = make_float4(acc[i][0], acc[i][1], acc[i][2], acc[i][3]);
            float4 hi = make_float4(acc[i][4], acc[i][5], acc[i][6], acc[i][7]);
            *(float4*)(out + (size_t)r * HDIM + c0) = lo;
            *(float4*)(out + (size_t)r * HDIM + c0 + 4) = hi;
        }
    }
}

// ---------------------------------------------------------------------------
// one wave per dst node; wave-uniform int4 metadata loads, 8 gathers in flight.
template <bool RELU_OUT>
__global__ __launch_bounds__(256) void agg_k(const int* __restrict__ rowptr,
                                             const int2* __restrict__ epack,
                                             const float* __restrict__ dinv,
                                             const float* __restrict__ hw,
                                             const float* __restrict__ b,
                                             float* __restrict__ h) {
    const int lane = threadIdx.x & 63;
    int node = (blockIdx.x * 256 + threadIdx.x) >> 6;
    if (node >= N_NODES) return;
    int e0 = rowptr[node], e1 = rowptr[node + 1];
    float dv = dinv[node];
    float acc = b[lane] + hw[(size_t)node * HDIM + lane] * dv * dv;

    int e = e0;
    if ((e & 1) && e < e1) {
        int2 m = epack[e];
        acc = fmaf(hw[(size_t)m.x * HDIM + lane], __int_as_float(m.y), acc);
        ++e;
    }
    for (; e + 8 <= e1; e += 8) {
        int4 m0 = *(const int4*)(epack + e);
        int4 m1 = *(const int4*)(epack + e + 2);
        int4 m2 = *(const int4*)(epack + e + 4);
        int4 m3 = *(const int4*)(epack + e + 6);
        float v0 = hw[(size_t)m0.x * HDIM + lane];
        float v1 = hw[(size_t)m0.z * HDIM + lane];
        float v2 = hw[(size_t)m1.x * HDIM + lane];
        float v3 = hw[(size_t)m1.z * HDIM + lane];
        float v4 = hw[(size_t)m2.x * HDIM + lane];
        float v5 = hw[(size_t)m2.z * HDIM + lane];
        float v6 = hw[(size_t)m3.x * HDIM + lane];
        float v7 = hw[(size_t)m3.z * HDIM + lane];
        acc = fmaf(v0, __int_as_float(m0.y), acc);
        acc = fmaf(v1, __int_as_float(m0.w), acc);
        acc = fmaf(v2, __int_as_float(m1.y), acc);
        acc = fmaf(v3, __int_as_float(m1.w), acc);
        acc = fmaf(v4, __int_as_float(m2.y), acc);
        acc = fmaf(v5, __int_as_float(m2.w), acc);
        acc = fmaf(v6, __int_as_float(m3.y), acc);
        acc = fmaf(v7, __int_as_float(m3.w), acc);
    }
    for (; e < e1; ++e) {
        int2 m = epack[e];
        acc = fmaf(hw[(size_t)m.x * HDIM + lane], __int_as_float(m.y), acc);
    }
    if (RELU_OUT) acc = fmaxf(acc, 0.0f);
    h[(size_t)node * HDIM + lane] = acc;
}

// ---------------------------------------------------------------------------
__global__ __launch_bounds__(256) void pool_k(const float* __restrict__ h,
                                              const int* __restrict__ batch,
                                              const float* __restrict__ lw,
                                              float* __restrict__ gsum,
                                              float* __restrict__ gcnt) {
    int i = blockIdx.x * blockDim.x + threadIdx.x;
    bool act = i < N_NODES;
    float dot = 0.0f;
    int g = -1;
    if (act) {
        g = batch[i];
        const float4* row = (const float4*)(h + (size_t)i * HDIM);
        const float4* w4  = (const float4*)lw;
#pragma unroll
        for (int q = 0; q < 16; ++q) {
            float4 v = row[q], w = w4[q];
            dot = fmaf(v.x, w.x, dot);
            dot = fmaf(v.y, w.y, dot);
            dot = fmaf(v.z, w.z, dot);
            dot = fmaf(v.w, w.w, dot);
        }
    }
    int g0 = __shfl(g, 0);
    bool uni = (__ballot(act && (g == g0)) == ~0ULL);
    if (uni) {
        for (int o = 32; o > 0; o >>= 1) dot += __shfl_down(dot, o);
        if ((threadIdx.x & 63) == 0) {
            atomicAdd(&gsum[g0], dot);
            atomicAdd(&gcnt[g0], 64.0f);
        }
    } else if (act) {
        atomicAdd(&gsum[g], dot);
        atomicAdd(&gcnt[g], 1.0f);
    }
}

__global__ void final_k(float* __restrict__ out, const float* __restrict__ gsum,
                        const float* __restrict__ gcnt, const float* __restrict__ lb) {
    int g = blockIdx.x * blockDim.x + threadIdx.x;
    if (g < N_GRAPHS) out[g] = gsum[g] / fmaxf(gcnt[g], 1.0f) + lb[0];
}

// ---------------------------------------------------------------------------
extern "C" void kernel_launch(void* const* d_in, const int* in_sizes, int n_in,
                              void* d_out, int out_size, void* d_ws, size_t ws_size,
                              hipStream_t stream) {
    const float* x     = (const float*)d_in[0];
    const int*   eidx  = (const int*)d_in[1];   // [2, E] int32
    const int*   batch = (const int*)d_in[3];
    const float* W1 = (const float*)d_in[4];
    const float* b1 = (const float*)d_in[5];
    const float* W2 = (const float*)d_in[6];
    const float* b2 = (const float*)d_in[7];
    const float* W3 = (const float*)d_in[8];
    const float* b3 = (const float*)d_in[9];
    const float* lin_w = (const float*)d_in[10];
    const float* lin_b = (const float*)d_in[11];
    float* out = (float*)d_out;

    const int* src = eidx;
    const int* dst = eidx + N_EDGES;

    float* ws     = (float*)d_ws;
    float* dinv   = ws;                         // 100352 f
    int*   rowptr = (int*)(ws + 100352);        // 100352 i (needs 100001)
    int*   coffs  = rowptr + 100352;            // 12544 (needs NSEGX+1)
    int*   ccntp  = coffs + 12544;              // NSEGX*PAD = 200192
    int*   ccurp  = ccntp + 200192;             // 200192
    int2*  epack  = (int2*)(ccurp + 200192);    // 1.6M int2 (16B-aligned: 613632%4==0)
    float* bufA   = (float*)(epack + N_EDGES);  // 6.4M f
    float* bufB   = bufA + 6400000;             // 6.4M f
    float* gsum   = bufB + 6400000;             // 1024
    float* gcnt   = gsum + 1024;                // 1024   (~66.5 MB total)
    int*   eC     = (int*)bufA;                 // 1.6M i, aliases bufA (dead before gemm1)

    // ---- CSR build (once; reused by all 3 layers) ----
    zero_k<<<512, 256, 0, stream>>>(ccntp, gsum, gcnt);
    coarse_hist_k<<<NBLK_AB, 256, 0, stream>>>(dst, ccntp);
    coarse_scan_k<<<1, 1024, 0, stream>>>(ccntp, coffs, ccurp);
    coarse_scatter_k<<<NBLK_AB, 256, 0, stream>>>(src, dst, ccurp, eC);
    bucket_count_k<<<NCOARSE, 256, 0, stream>>>(eC, coffs, rowptr, dinv);
    bucket_scatter_k<<<NCOARSE, 256, 0, stream>>>(eC, coffs, rowptr, dinv, epack);

    // ---- 3 GCN layers (relu folded into agg store) ----
    gemm_k<F_IN><<<1563, 256, 0, stream>>>(x, W1, bufA);
    agg_k<true><<<25000, 256, 0, stream>>>(rowptr, epack, dinv, bufA, b1, bufB);

    gemm_k<HDIM><<<1563, 256, 0, stream>>>(bufB, W2, bufA);
    agg_k<true><<<25000, 256, 0, stream>>>(rowptr, epack, dinv, bufA, b2, bufB);

    gemm_k<HDIM><<<1563, 256, 0, stream>>>(bufB, W3, bufA);
    agg_k<false><<<25000, 256, 0, stream>>>(rowptr, epack, dinv, bufA, b3, bufB);

    // ---- pool + head ----
    pool_k<<<(N_NODES + 255) / 256, 256, 0, stream>>>(bufB, batch, lin_w, gsum, gcnt);
    final_k<<<(N_GRAPHS + 255) / 256, 256, 0, stream>>>(out, gsum, gcnt, lin_b);
}

// Round 7
// 653.451 us; speedup vs baseline: 1.1725x; 1.0893x over previous
//
#include <hip/hip_runtime.h>

#define N_NODES 100000
#define N_EDGES 1600000
#define N_GRAPHS 1024
#define F_IN 128
#define HDIM 64
#define NCOARSE 391          // ceil(100000 / 256) dst>>8 buckets
#define XS 32                // segments per bucket (blockIdx & 31)
#define PAD 16               // ints per counter -> one 64B line each
#define NSEGX (NCOARSE * XS) // 12512
#define SPT 13               // scan elements per thread (13*1024 >= 12512+1)
#define NBLK_AB 1024
#define EPB 1563             // ceil(N_EDGES / NBLK_AB)

// ---------------------------------------------------------------------------
__global__ void zero_k(int* __restrict__ ccntp, float* __restrict__ gsum,
                       float* __restrict__ gcnt) {
    int i = blockIdx.x * blockDim.x + threadIdx.x;
    int stride = gridDim.x * blockDim.x;
    for (int j = i; j < NSEGX * PAD; j += stride) ccntp[j] = 0;
    for (int j = i; j < N_GRAPHS; j += stride) { gsum[j] = 0.0f; gcnt[j] = 0.0f; }
}

// per-block LDS coarse histogram; merge into padded per-(bucket,seg) counters
__global__ __launch_bounds__(256) void coarse_hist_k(const int* __restrict__ dst,
                                                     int* __restrict__ ccntp) {
    __shared__ int hist[NCOARSE];
    for (int i = threadIdx.x; i < NCOARSE; i += 256) hist[i] = 0;
    __syncthreads();
    int b = blockIdx.x;
    int e0 = b * EPB, e1 = min(e0 + EPB, N_EDGES);
    for (int e = e0 + threadIdx.x; e < e1; e += 256)
        atomicAdd(&hist[dst[e] >> 8], 1);
    __syncthreads();
    int x = b & (XS - 1);
    for (int c = threadIdx.x; c < NCOARSE; c += 256) {
        int v = hist[c];
        if (v) atomicAdd(&ccntp[(c * XS + x) * PAD], v);
    }
}

// exclusive scan of 12512 padded segment counts -> coffs (compact) + ccurp (padded)
__global__ __launch_bounds__(1024) void coarse_scan_k(const int* __restrict__ ccntp,
                                                      int* __restrict__ coffs,
                                                      int* __restrict__ ccurp) {
    __shared__ int tsum[1024];
    int t = threadIdx.x;
    int s = 0;
    for (int j = 0; j < SPT; ++j) {
        int idx = t * SPT + j;
        if (idx < NSEGX) s += ccntp[idx * PAD];
    }
    tsum[t] = s;
    __syncthreads();
    for (int o = 1; o < 1024; o <<= 1) {
        int add = (t >= o) ? tsum[t - o] : 0;
        __syncthreads();
        tsum[t] += add;
        __syncthreads();
    }
    int excl = tsum[t] - s;
    for (int j = 0; j < SPT; ++j) {
        int idx = t * SPT + j;
        if (idx < NSEGX) {
            int v = ccntp[idx * PAD];
            coffs[idx] = excl;
            ccurp[idx * PAD] = excl;
            excl += v;
        }
    }
    if (t == 1023) coffs[NSEGX] = tsum[1023];
}

// coarse scatter: 4B code (src | dstoff<<17) via padded line-exclusive cursors
__global__ __launch_bounds__(256) void coarse_scatter_k(const int* __restrict__ src,
                                                        const int* __restrict__ dst,
                                                        int* __restrict__ ccurp,
                                                        int* __restrict__ eC) {
    int b = blockIdx.x, x = b & (XS - 1);
    int e0 = b * EPB, e1 = min(e0 + EPB, N_EDGES);
    for (int e = e0 + threadIdx.x; e < e1; e += 256) {
        int s = src[e], d = dst[e];
        int pos = atomicAdd(&ccurp[((d >> 8) * XS + x) * PAD], 1);
        eC[pos] = s | ((d & 255) << 17);
    }
}

// per bucket: node counts (LDS) -> rowptr + dinv
__global__ __launch_bounds__(256) void bucket_count_k(const int* __restrict__ eC,
                                                      const int* __restrict__ coffs,
                                                      int* __restrict__ rowptr,
                                                      float* __restrict__ dinv) {
    __shared__ int cnt[256];
    __shared__ int sc[256];
    int c = blockIdx.x, t = threadIdx.x;
    cnt[t] = 0;
    __syncthreads();
    int s0 = coffs[c * XS], s1 = coffs[c * XS + XS];  // bucket's segs adjacent
    for (int e = s0 + t; e < s1; e += 256)
        atomicAdd(&cnt[(eC[e] >> 17) & 255], 1);
    __syncthreads();
    int v = cnt[t];
    sc[t] = v;
    __syncthreads();
    for (int o = 1; o < 256; o <<= 1) {
        int add = (t >= o) ? sc[t - o] : 0;
        __syncthreads();
        sc[t] += add;
        __syncthreads();
    }
    int node = c * 256 + t;
    if (node < N_NODES) {
        rowptr[node] = s0 + sc[t] - v;
        dinv[node] = rsqrtf((float)v + 1.0f);  // +1 self loop
    }
    if (node == N_NODES - 1) rowptr[N_NODES] = s1;
}

// per bucket: final scatter with norm; writes land in a block-exclusive region
__global__ __launch_bounds__(256) void bucket_scatter_k(const int* __restrict__ eC,
                                                        const int* __restrict__ coffs,
                                                        const int* __restrict__ rowptr,
                                                        const float* __restrict__ dinv,
                                                        int2* __restrict__ epack) {
    __shared__ int cur[256];
    __shared__ float dv[256];
    int c = blockIdx.x, t = threadIdx.x;
    int node = c * 256 + t;
    cur[t] = (node < N_NODES) ? rowptr[node] : 0;
    dv[t] = (node < N_NODES) ? dinv[node] : 0.0f;
    __syncthreads();
    int s0 = coffs[c * XS], s1 = coffs[c * XS + XS];
    for (int e = s0 + t; e < s1; e += 256) {
        int u = eC[e];
        int s = u & 0x1FFFF;
        int doff = (u >> 17) & 255;
        float nm = dinv[s] * dv[doff];
        int pos = atomicAdd(&cur[doff], 1);
        epack[pos] = make_int2(s, __float_as_int(nm));
    }
}

// ---------------------------------------------------------------------------
// GEMM: W staged in LDS (float4 reads, 2-way bank alias = free); A from global
// (2 dup-lane loads/chunk only). Thread: 2 rows x 8 cols, 64 FMA per 4-k chunk.
#define FMA8(av, wl, wh, accrow)                       \
    accrow[0] = fmaf(av, wl.x, accrow[0]);             \
    accrow[1] = fmaf(av, wl.y, accrow[1]);             \
    accrow[2] = fmaf(av, wl.z, accrow[2]);             \
    accrow[3] = fmaf(av, wl.w, accrow[3]);             \
    accrow[4] = fmaf(av, wh.x, accrow[4]);             \
    accrow[5] = fmaf(av, wh.y, accrow[5]);             \
    accrow[6] = fmaf(av, wh.z, accrow[6]);             \
    accrow[7] = fmaf(av, wh.w, accrow[7]);

template <int K>
__global__ __launch_bounds__(256) void gemm_k(const float* __restrict__ A,
                                              const float* __restrict__ W,
                                              float* __restrict__ out) {
    __shared__ float Wl[K * 64];
    for (int i = threadIdx.x * 4; i < K * 64; i += 1024)
        *(float4*)&Wl[i] = *(const float4*)&W[i];
    __syncthreads();

    const int tx = threadIdx.x & 7;
    const int ty = threadIdx.x >> 3;   // 0..31
    const int c0 = tx * 8;
    const int r0 = blockIdx.x * 64 + ty * 2;
    float acc[2][8];
#pragma unroll
    for (int i = 0; i < 2; ++i)
#pragma unroll
        for (int j = 0; j < 8; ++j) acc[i][j] = 0.0f;

#pragma unroll 2
    for (int kc = 0; kc < K; kc += 4) {
        float4 a[2];
#pragma unroll
        for (int i = 0; i < 2; ++i) {
            int r = r0 + i;
            a[i] = (r < N_NODES) ? *(const float4*)(A + (size_t)r * K + kc)
                                 : make_float4(0.f, 0.f, 0.f, 0.f);
        }
        float4 wlo[4], whi[4];
#pragma unroll
        for (int j = 0; j < 4; ++j) {
            wlo[j] = *(const float4*)&Wl[(kc + j) * HDIM + c0];
            whi[j] = *(const float4*)&Wl[(kc + j) * HDIM + c0 + 4];
        }
#pragma unroll
        for (int i = 0; i < 2; ++i) {
            FMA8(a[i].x, wlo[0], whi[0], acc[i]);
            FMA8(a[i].y, wlo[1], whi[1], acc[i]);
            FMA8(a[i].z, wlo[2], whi[2], acc[i]);
            FMA8(a[i].w, wlo[3], whi[3], acc[i]);
        }
    }
#pragma unroll
    for (int i = 0; i < 2; ++i) {
        int r = r0 + i;
        if (r < N_NODES) {
            float4 lo = make_float4(acc[i][0], acc[i][1], acc[i][2], acc[i][3]);
            float4 hi = make_float4(acc[i][4], acc[i][5], acc[i][6], acc[i][7]);
            *(float4*)(out + (size_t)r * HDIM + c0) = lo;
            *(float4*)(out + (size_t)r * HDIM + c0 + 4) = hi;
        }
    }
}

// ---------------------------------------------------------------------------
// one wave per dst node; wave-uniform int4 metadata loads, 8 gathers in flight.
template <bool RELU_OUT>
__global__ __launch_bounds__(256) void agg_k(const int* __restrict__ rowptr,
                                             const int2* __restrict__ epack,
                                             const float* __restrict__ dinv,
                                             const float* __restrict__ hw,
                                             const float* __restrict__ b,
                                             float* __restrict__ h) {
    const int lane = threadIdx.x & 63;
    int node = (blockIdx.x * 256 + threadIdx.x) >> 6;
    if (node >= N_NODES) return;
    int e0 = rowptr[node], e1 = rowptr[node + 1];
    float dv = dinv[node];
    float acc = b[lane] + hw[(size_t)node * HDIM + lane] * dv * dv;

    int e = e0;
    if ((e & 1) && e < e1) {
        int2 m = epack[e];
        acc = fmaf(hw[(size_t)m.x * HDIM + lane], __int_as_float(m.y), acc);
        ++e;
    }
    for (; e + 8 <= e1; e += 8) {
        int4 m0 = *(const int4*)(epack + e);
        int4 m1 = *(const int4*)(epack + e + 2);
        int4 m2 = *(const int4*)(epack + e + 4);
        int4 m3 = *(const int4*)(epack + e + 6);
        float v0 = hw[(size_t)m0.x * HDIM + lane];
        float v1 = hw[(size_t)m0.z * HDIM + lane];
        float v2 = hw[(size_t)m1.x * HDIM + lane];
        float v3 = hw[(size_t)m1.z * HDIM + lane];
        float v4 = hw[(size_t)m2.x * HDIM + lane];
        float v5 = hw[(size_t)m2.z * HDIM + lane];
        float v6 = hw[(size_t)m3.x * HDIM + lane];
        float v7 = hw[(size_t)m3.z * HDIM + lane];
        acc = fmaf(v0, __int_as_float(m0.y), acc);
        acc = fmaf(v1, __int_as_float(m0.w), acc);
        acc = fmaf(v2, __int_as_float(m1.y), acc);
        acc = fmaf(v3, __int_as_float(m1.w), acc);
        acc = fmaf(v4, __int_as_float(m2.y), acc);
        acc = fmaf(v5, __int_as_float(m2.w), acc);
        acc = fmaf(v6, __int_as_float(m3.y), acc);
        acc = fmaf(v7, __int_as_float(m3.w), acc);
    }
    for (; e < e1; ++e) {
        int2 m = epack[e];
        acc = fmaf(hw[(size_t)m.x * HDIM + lane], __int_as_float(m.y), acc);
    }
    if (RELU_OUT) acc = fmaxf(acc, 0.0f);
    h[(size_t)node * HDIM + lane] = acc;
}

// ---------------------------------------------------------------------------
__global__ __launch_bounds__(256) void pool_k(const float* __restrict__ h,
                                              const int* __restrict__ batch,
                                              const float* __restrict__ lw,
                                              float* __restrict__ gsum,
                                              float* __restrict__ gcnt) {
    int i = blockIdx.x * blockDim.x + threadIdx.x;
    bool act = i < N_NODES;
    float dot = 0.0f;
    int g = -1;
    if (act) {
        g = batch[i];
        const float4* row = (const float4*)(h + (size_t)i * HDIM);
        const float4* w4  = (const float4*)lw;
#pragma unroll
        for (int q = 0; q < 16; ++q) {
            float4 v = row[q], w = w4[q];
            dot = fmaf(v.x, w.x, dot);
            dot = fmaf(v.y, w.y, dot);
            dot = fmaf(v.z, w.z, dot);
            dot = fmaf(v.w, w.w, dot);
        }
    }
    int g0 = __shfl(g, 0);
    bool uni = (__ballot(act && (g == g0)) == ~0ULL);
    if (uni) {
        for (int o = 32; o > 0; o >>= 1) dot += __shfl_down(dot, o);
        if ((threadIdx.x & 63) == 0) {
            atomicAdd(&gsum[g0], dot);
            atomicAdd(&gcnt[g0], 64.0f);
        }
    } else if (act) {
        atomicAdd(&gsum[g], dot);
        atomicAdd(&gcnt[g], 1.0f);
    }
}

__global__ void final_k(float* __restrict__ out, const float* __restrict__ gsum,
                        const float* __restrict__ gcnt, const float* __restrict__ lb) {
    int g = blockIdx.x * blockDim.x + threadIdx.x;
    if (g < N_GRAPHS) out[g] = gsum[g] / fmaxf(gcnt[g], 1.0f) + lb[0];
}

// ---------------------------------------------------------------------------
extern "C" void kernel_launch(void* const* d_in, const int* in_sizes, int n_in,
                              void* d_out, int out_size, void* d_ws, size_t ws_size,
                              hipStream_t stream) {
    const float* x     = (const float*)d_in[0];
    const int*   eidx  = (const int*)d_in[1];   // [2, E] int32
    const int*   batch = (const int*)d_in[3];
    const float* W1 = (const float*)d_in[4];
    const float* b1 = (const float*)d_in[5];
    const float* W2 = (const float*)d_in[6];
    const float* b2 = (const float*)d_in[7];
    const float* W3 = (const float*)d_in[8];
    const float* b3 = (const float*)d_in[9];
    const float* lin_w = (const float*)d_in[10];
    const float* lin_b = (const float*)d_in[11];
    float* out = (float*)d_out;

    const int* src = eidx;
    const int* dst = eidx + N_EDGES;

    float* ws     = (float*)d_ws;
    float* dinv   = ws;                         // 100352 f
    int*   rowptr = (int*)(ws + 100352);        // 100352 i (needs 100001)
    int*   coffs  = rowptr + 100352;            // 12544 (needs NSEGX+1)
    int*   ccntp  = coffs + 12544;              // NSEGX*PAD = 200192
    int*   ccurp  = ccntp + 200192;             // 200192
    int2*  epack  = (int2*)(ccurp + 200192);    // 1.6M int2 (16B-aligned)
    float* bufA   = (float*)(epack + N_EDGES);  // 6.4M f
    float* bufB   = bufA + 6400000;             // 6.4M f
    float* gsum   = bufB + 6400000;             // 1024
    float* gcnt   = gsum + 1024;                // 1024   (~66.5 MB total)
    int*   eC     = (int*)bufA;                 // 1.6M i, aliases bufA (dead before gemm1)

    // ---- CSR build (once; reused by all 3 layers) ----
    zero_k<<<512, 256, 0, stream>>>(ccntp, gsum, gcnt);
    coarse_hist_k<<<NBLK_AB, 256, 0, stream>>>(dst, ccntp);
    coarse_scan_k<<<1, 1024, 0, stream>>>(ccntp, coffs, ccurp);
    coarse_scatter_k<<<NBLK_AB, 256, 0, stream>>>(src, dst, ccurp, eC);
    bucket_count_k<<<NCOARSE, 256, 0, stream>>>(eC, coffs, rowptr, dinv);
    bucket_scatter_k<<<NCOARSE, 256, 0, stream>>>(eC, coffs, rowptr, dinv, epack);

    // ---- 3 GCN layers (relu folded into agg store) ----
    gemm_k<F_IN><<<1563, 256, 0, stream>>>(x, W1, bufA);
    agg_k<true><<<25000, 256, 0, stream>>>(rowptr, epack, dinv, bufA, b1, bufB);

    gemm_k<HDIM><<<1563, 256, 0, stream>>>(bufB, W2, bufA);
    agg_k<true><<<25000, 256, 0, stream>>>(rowptr, epack, dinv, bufA, b2, bufB);

    gemm_k<HDIM><<<1563, 256, 0, stream>>>(bufB, W3, bufA);
    agg_k<false><<<25000, 256, 0, stream>>>(rowptr, epack, dinv, bufA, b3, bufB);

    // ---- pool + head ----
    pool_k<<<(N_NODES + 255) / 256, 256, 0, stream>>>(bufB, batch, lin_w, gsum, gcnt);
    final_k<<<(N_GRAPHS + 255) / 256, 256, 0, stream>>>(out, gsum, gcnt, lin_b);
}

// Round 8
// 625.605 us; speedup vs baseline: 1.2247x; 1.0445x over previous
//
#include <hip/hip_runtime.h>
#include <hip/hip_fp16.h>

#define N_NODES 100000
#define N_EDGES 1600000
#define N_GRAPHS 1024
#define F_IN 128
#define HDIM 64
#define NCOARSE 391          // ceil(100000 / 256) dst>>8 buckets
#define XS 32                // segments per bucket (blockIdx & 31)
#define PAD 16               // ints per counter -> one 64B line each
#define NSEGX (NCOARSE * XS) // 12512
#define SPT 13               // scan elements per thread (13*1024 >= 12512+1)
#define NBLK_AB 1024
#define EPB 1563             // ceil(N_EDGES / NBLK_AB)

// ---------------------------------------------------------------------------
__global__ void zero_k(int* __restrict__ ccntp, float* __restrict__ gsum,
                       float* __restrict__ gcnt) {
    int i = blockIdx.x * blockDim.x + threadIdx.x;
    int stride = gridDim.x * blockDim.x;
    for (int j = i; j < NSEGX * PAD; j += stride) ccntp[j] = 0;
    for (int j = i; j < N_GRAPHS; j += stride) { gsum[j] = 0.0f; gcnt[j] = 0.0f; }
}

// per-block LDS coarse histogram; merge into padded per-(bucket,seg) counters
__global__ __launch_bounds__(256) void coarse_hist_k(const int* __restrict__ dst,
                                                     int* __restrict__ ccntp) {
    __shared__ int hist[NCOARSE];
    for (int i = threadIdx.x; i < NCOARSE; i += 256) hist[i] = 0;
    __syncthreads();
    int b = blockIdx.x;
    int e0 = b * EPB, e1 = min(e0 + EPB, N_EDGES);
    for (int e = e0 + threadIdx.x; e < e1; e += 256)
        atomicAdd(&hist[dst[e] >> 8], 1);
    __syncthreads();
    int x = b & (XS - 1);
    for (int c = threadIdx.x; c < NCOARSE; c += 256) {
        int v = hist[c];
        if (v) atomicAdd(&ccntp[(c * XS + x) * PAD], v);
    }
}

// exclusive scan of 12512 padded segment counts -> coffs (compact) + ccurp (padded)
__global__ __launch_bounds__(1024) void coarse_scan_k(const int* __restrict__ ccntp,
                                                      int* __restrict__ coffs,
                                                      int* __restrict__ ccurp) {
    __shared__ int tsum[1024];
    int t = threadIdx.x;
    int s = 0;
    for (int j = 0; j < SPT; ++j) {
        int idx = t * SPT + j;
        if (idx < NSEGX) s += ccntp[idx * PAD];
    }
    tsum[t] = s;
    __syncthreads();
    for (int o = 1; o < 1024; o <<= 1) {
        int add = (t >= o) ? tsum[t - o] : 0;
        __syncthreads();
        tsum[t] += add;
        __syncthreads();
    }
    int excl = tsum[t] - s;
    for (int j = 0; j < SPT; ++j) {
        int idx = t * SPT + j;
        if (idx < NSEGX) {
            int v = ccntp[idx * PAD];
            coffs[idx] = excl;
            ccurp[idx * PAD] = excl;
            excl += v;
        }
    }
    if (t == 1023) coffs[NSEGX] = tsum[1023];
}

// coarse scatter: 4B code (src | dstoff<<17) via padded line-exclusive cursors
__global__ __launch_bounds__(256) void coarse_scatter_k(const int* __restrict__ src,
                                                        const int* __restrict__ dst,
                                                        int* __restrict__ ccurp,
                                                        int* __restrict__ eC) {
    int b = blockIdx.x, x = b & (XS - 1);
    int e0 = b * EPB, e1 = min(e0 + EPB, N_EDGES);
    for (int e = e0 + threadIdx.x; e < e1; e += 256) {
        int s = src[e], d = dst[e];
        int pos = atomicAdd(&ccurp[((d >> 8) * XS + x) * PAD], 1);
        eC[pos] = s | ((d & 255) << 17);
    }
}

// per bucket: node counts (LDS) -> rowptr + dinv
__global__ __launch_bounds__(256) void bucket_count_k(const int* __restrict__ eC,
                                                      const int* __restrict__ coffs,
                                                      int* __restrict__ rowptr,
                                                      float* __restrict__ dinv) {
    __shared__ int cnt[256];
    __shared__ int sc[256];
    int c = blockIdx.x, t = threadIdx.x;
    cnt[t] = 0;
    __syncthreads();
    int s0 = coffs[c * XS], s1 = coffs[c * XS + XS];  // bucket's segs adjacent
    for (int e = s0 + t; e < s1; e += 256)
        atomicAdd(&cnt[(eC[e] >> 17) & 255], 1);
    __syncthreads();
    int v = cnt[t];
    sc[t] = v;
    __syncthreads();
    for (int o = 1; o < 256; o <<= 1) {
        int add = (t >= o) ? sc[t - o] : 0;
        __syncthreads();
        sc[t] += add;
        __syncthreads();
    }
    int node = c * 256 + t;
    if (node < N_NODES) {
        rowptr[node] = s0 + sc[t] - v;
        dinv[node] = rsqrtf((float)v + 1.0f);  // +1 self loop
    }
    if (node == N_NODES - 1) rowptr[N_NODES] = s1;
}

// per bucket: final scatter with norm; writes land in a block-exclusive region
__global__ __launch_bounds__(256) void bucket_scatter_k(const int* __restrict__ eC,
                                                        const int* __restrict__ coffs,
                                                        const int* __restrict__ rowptr,
                                                        const float* __restrict__ dinv,
                                                        int2* __restrict__ epack) {
    __shared__ int cur[256];
    __shared__ float dv[256];
    int c = blockIdx.x, t = threadIdx.x;
    int node = c * 256 + t;
    cur[t] = (node < N_NODES) ? rowptr[node] : 0;
    dv[t] = (node < N_NODES) ? dinv[node] : 0.0f;
    __syncthreads();
    int s0 = coffs[c * XS], s1 = coffs[c * XS + XS];
    for (int e = s0 + t; e < s1; e += 256) {
        int u = eC[e];
        int s = u & 0x1FFFF;
        int doff = (u >> 17) & 255;
        float nm = dinv[s] * dv[doff];
        int pos = atomicAdd(&cur[doff], 1);
        epack[pos] = make_int2(s, __float_as_int(nm));
    }
}

// ---------------------------------------------------------------------------
// GEMM: W staged in LDS; A fp32 from global; OUT fp16 (halves store + later
// gather traffic). Thread: 2 rows x 8 cols, 64 FMA per 4-k chunk.
#define FMA8(av, wl, wh, accrow)                       \
    accrow[0] = fmaf(av, wl.x, accrow[0]);             \
    accrow[1] = fmaf(av, wl.y, accrow[1]);             \
    accrow[2] = fmaf(av, wl.z, accrow[2]);             \
    accrow[3] = fmaf(av, wl.w, accrow[3]);             \
    accrow[4] = fmaf(av, wh.x, accrow[4]);             \
    accrow[5] = fmaf(av, wh.y, accrow[5]);             \
    accrow[6] = fmaf(av, wh.z, accrow[6]);             \
    accrow[7] = fmaf(av, wh.w, accrow[7]);

template <int K>
__global__ __launch_bounds__(256) void gemm_k(const float* __restrict__ A,
                                              const float* __restrict__ W,
                                              __half* __restrict__ out) {
    __shared__ float Wl[K * 64];
    for (int i = threadIdx.x * 4; i < K * 64; i += 1024)
        *(float4*)&Wl[i] = *(const float4*)&W[i];
    __syncthreads();

    const int tx = threadIdx.x & 7;
    const int ty = threadIdx.x >> 3;   // 0..31
    const int c0 = tx * 8;
    const int r0 = blockIdx.x * 64 + ty * 2;
    float acc[2][8];
#pragma unroll
    for (int i = 0; i < 2; ++i)
#pragma unroll
        for (int j = 0; j < 8; ++j) acc[i][j] = 0.0f;

#pragma unroll 2
    for (int kc = 0; kc < K; kc += 4) {
        float4 a[2];
#pragma unroll
        for (int i = 0; i < 2; ++i) {
            int r = r0 + i;
            a[i] = (r < N_NODES) ? *(const float4*)(A + (size_t)r * K + kc)
                                 : make_float4(0.f, 0.f, 0.f, 0.f);
        }
        float4 wlo[4], whi[4];
#pragma unroll
        for (int j = 0; j < 4; ++j) {
            wlo[j] = *(const float4*)&Wl[(kc + j) * HDIM + c0];
            whi[j] = *(const float4*)&Wl[(kc + j) * HDIM + c0 + 4];
        }
#pragma unroll
        for (int i = 0; i < 2; ++i) {
            FMA8(a[i].x, wlo[0], whi[0], acc[i]);
            FMA8(a[i].y, wlo[1], whi[1], acc[i]);
            FMA8(a[i].z, wlo[2], whi[2], acc[i]);
            FMA8(a[i].w, wlo[3], whi[3], acc[i]);
        }
    }
#pragma unroll
    for (int i = 0; i < 2; ++i) {
        int r = r0 + i;
        if (r < N_NODES) {
            __half hb[8];
#pragma unroll
            for (int j = 0; j < 8; ++j) hb[j] = __float2half(acc[i][j]);
            *(uint4*)(out + (size_t)r * HDIM + c0) = *(uint4*)hb;  // 16B store
        }
    }
}

// ---------------------------------------------------------------------------
// one wave per dst node; wave-uniform int4 metadata loads, 8 fp16 gathers
// (128B/row) in flight; fp32 accumulate; fp32 store.
template <bool RELU_OUT>
__global__ __launch_bounds__(256) void agg_k(const int* __restrict__ rowptr,
                                             const int2* __restrict__ epack,
                                             const float* __restrict__ dinv,
                                             const __half* __restrict__ hw,
                                             const float* __restrict__ b,
                                             float* __restrict__ h) {
    const int lane = threadIdx.x & 63;
    int node = (blockIdx.x * 256 + threadIdx.x) >> 6;
    if (node >= N_NODES) return;
    int e0 = rowptr[node], e1 = rowptr[node + 1];
    float dv = dinv[node];
    float acc = b[lane] + __half2float(hw[(size_t)node * HDIM + lane]) * dv * dv;

    int e = e0;
    if ((e & 1) && e < e1) {
        int2 m = epack[e];
        acc = fmaf(__half2float(hw[(size_t)m.x * HDIM + lane]),
                   __int_as_float(m.y), acc);
        ++e;
    }
    for (; e + 8 <= e1; e += 8) {
        int4 m0 = *(const int4*)(epack + e);
        int4 m1 = *(const int4*)(epack + e + 2);
        int4 m2 = *(const int4*)(epack + e + 4);
        int4 m3 = *(const int4*)(epack + e + 6);
        float v0 = __half2float(hw[(size_t)m0.x * HDIM + lane]);
        float v1 = __half2float(hw[(size_t)m0.z * HDIM + lane]);
        float v2 = __half2float(hw[(size_t)m1.x * HDIM + lane]);
        float v3 = __half2float(hw[(size_t)m1.z * HDIM + lane]);
        float v4 = __half2float(hw[(size_t)m2.x * HDIM + lane]);
        float v5 = __half2float(hw[(size_t)m2.z * HDIM + lane]);
        float v6 = __half2float(hw[(size_t)m3.x * HDIM + lane]);
        float v7 = __half2float(hw[(size_t)m3.z * HDIM + lane]);
        acc = fmaf(v0, __int_as_float(m0.y), acc);
        acc = fmaf(v1, __int_as_float(m0.w), acc);
        acc = fmaf(v2, __int_as_float(m1.y), acc);
        acc = fmaf(v3, __int_as_float(m1.w), acc);
        acc = fmaf(v4, __int_as_float(m2.y), acc);
        acc = fmaf(v5, __int_as_float(m2.w), acc);
        acc = fmaf(v6, __int_as_float(m3.y), acc);
        acc = fmaf(v7, __int_as_float(m3.w), acc);
    }
    for (; e < e1; ++e) {
        int2 m = epack[e];
        acc = fmaf(__half2float(hw[(size_t)m.x * HDIM + lane]),
                   __int_as_float(m.y), acc);
    }
    if (RELU_OUT) acc = fmaxf(acc, 0.0f);
    h[(size_t)node * HDIM + lane] = acc;
}

// ---------------------------------------------------------------------------
__global__ __launch_bounds__(256) void pool_k(const float* __restrict__ h,
                                              const int* __restrict__ batch,
                                              const float* __restrict__ lw,
                                              float* __restrict__ gsum,
                                              float* __restrict__ gcnt) {
    int i = blockIdx.x * blockDim.x + threadIdx.x;
    bool act = i < N_NODES;
    float dot = 0.0f;
    int g = -1;
    if (act) {
        g = batch[i];
        const float4* row = (const float4*)(h + (size_t)i * HDIM);
        const float4* w4  = (const float4*)lw;
#pragma unroll
        for (int q = 0; q < 16; ++q) {
            float4 v = row[q], w = w4[q];
            dot = fmaf(v.x, w.x, dot);
            dot = fmaf(v.y, w.y, dot);
            dot = fmaf(v.z, w.z, dot);
            dot = fmaf(v.w, w.w, dot);
        }
    }
    int g0 = __shfl(g, 0);
    bool uni = (__ballot(act && (g == g0)) == ~0ULL);
    if (uni) {
        for (int o = 32; o > 0; o >>= 1) dot += __shfl_down(dot, o);
        if ((threadIdx.x & 63) == 0) {
            atomicAdd(&gsum[g0], dot);
            atomicAdd(&gcnt[g0], 64.0f);
        }
    } else if (act) {
        atomicAdd(&gsum[g], dot);
        atomicAdd(&gcnt[g], 1.0f);
    }
}

__global__ void final_k(float* __restrict__ out, const float* __restrict__ gsum,
                        const float* __restrict__ gcnt, const float* __restrict__ lb) {
    int g = blockIdx.x * blockDim.x + threadIdx.x;
    if (g < N_GRAPHS) out[g] = gsum[g] / fmaxf(gcnt[g], 1.0f) + lb[0];
}

// ---------------------------------------------------------------------------
extern "C" void kernel_launch(void* const* d_in, const int* in_sizes, int n_in,
                              void* d_out, int out_size, void* d_ws, size_t ws_size,
                              hipStream_t stream) {
    const float* x     = (const float*)d_in[0];
    const int*   eidx  = (const int*)d_in[1];   // [2, E] int32
    const int*   batch = (const int*)d_in[3];
    const float* W1 = (const float*)d_in[4];
    const float* b1 = (const float*)d_in[5];
    const float* W2 = (const float*)d_in[6];
    const float* b2 = (const float*)d_in[7];
    const float* W3 = (const float*)d_in[8];
    const float* b3 = (const float*)d_in[9];
    const float* lin_w = (const float*)d_in[10];
    const float* lin_b = (const float*)d_in[11];
    float* out = (float*)d_out;

    const int* src = eidx;
    const int* dst = eidx + N_EDGES;

    float*  ws     = (float*)d_ws;
    float*  dinv   = ws;                         // 100352 f
    int*    rowptr = (int*)(ws + 100352);        // 100352 i (needs 100001)
    int*    coffs  = rowptr + 100352;            // 12544 (needs NSEGX+1)
    int*    ccntp  = coffs + 12544;              // NSEGX*PAD = 200192
    int*    ccurp  = ccntp + 200192;             // 200192
    int2*   epack  = (int2*)(ccurp + 200192);    // 1.6M int2 (16B-aligned)
    __half* bufH   = (__half*)(epack + N_EDGES); // 6.4M halfs (12.8 MB) gemm-out
    float*  bufF   = (float*)(bufH + 6400000);   // 6.4M f (25.6 MB) agg-out
    float*  gsum   = bufF + 6400000;             // 1024
    float*  gcnt   = gsum + 1024;                // 1024   (~54 MB total)
    int*    eC     = (int*)bufH;                 // 1.6M i, aliases bufH (dead before gemm1)

    // ---- CSR build (once; reused by all 3 layers) ----
    zero_k<<<512, 256, 0, stream>>>(ccntp, gsum, gcnt);
    coarse_hist_k<<<NBLK_AB, 256, 0, stream>>>(dst, ccntp);
    coarse_scan_k<<<1, 1024, 0, stream>>>(ccntp, coffs, ccurp);
    coarse_scatter_k<<<NBLK_AB, 256, 0, stream>>>(src, dst, ccurp, eC);
    bucket_count_k<<<NCOARSE, 256, 0, stream>>>(eC, coffs, rowptr, dinv);
    bucket_scatter_k<<<NCOARSE, 256, 0, stream>>>(eC, coffs, rowptr, dinv, epack);

    // ---- 3 GCN layers (relu folded into agg store) ----
    gemm_k<F_IN><<<1563, 256, 0, stream>>>(x, W1, bufH);
    agg_k<true><<<25000, 256, 0, stream>>>(rowptr, epack, dinv, bufH, b1, bufF);

    gemm_k<HDIM><<<1563, 256, 0, stream>>>(bufF, W2, bufH);
    agg_k<true><<<25000, 256, 0, stream>>>(rowptr, epack, dinv, bufH, b2, bufF);

    gemm_k<HDIM><<<1563, 256, 0, stream>>>(bufF, W3, bufH);
    agg_k<false><<<25000, 256, 0, stream>>>(rowptr, epack, dinv, bufH, b3, bufF);

    // ---- pool + head ----
    pool_k<<<(N_NODES + 255) / 256, 256, 0, stream>>>(bufF, batch, lin_w, gsum, gcnt);
    final_k<<<(N_GRAPHS + 255) / 256, 256, 0, stream>>>(out, gsum, gcnt, lin_b);
}

// Round 9
// 523.554 us; speedup vs baseline: 1.4635x; 1.1949x over previous
//
#include <hip/hip_runtime.h>
#include <hip/hip_fp16.h>

#define N_NODES 100000
#define N_EDGES 1600000
#define N_GRAPHS 1024
#define F_IN 128
#define HDIM 64
#define NCOARSE 391            // dst>>8 buckets
#define NBLK_AB 1024
#define EPB 1563               // ceil(N_EDGES / NBLK_AB)
#define NH (NCOARSE * 8 * 128) // 400384 = per-(bucket,g,j) histogram
#define NSCN (NH / 256)        // 1564 scan blocks

// ---------------------------------------------------------------------------
__global__ void zero_k(float* __restrict__ gsum, float* __restrict__ gcnt) {
    int i = blockIdx.x * blockDim.x + threadIdx.x;
    if (i < N_GRAPHS) { gsum[i] = 0.0f; gcnt[i] = 0.0f; }
}

// per-block LDS coarse histogram -> H[(c*8+g)*128+j], g=b&7, j=b>>3
__global__ __launch_bounds__(256) void coarse_hist_k(const int* __restrict__ dst,
                                                     int* __restrict__ H) {
    __shared__ int hist[NCOARSE];
    for (int i = threadIdx.x; i < NCOARSE; i += 256) hist[i] = 0;
    __syncthreads();
    int b = blockIdx.x;
    int e0 = b * EPB, e1 = min(e0 + EPB, N_EDGES);
    for (int e = e0 + threadIdx.x; e < e1; e += 256)
        atomicAdd(&hist[dst[e] >> 8], 1);
    __syncthreads();
    int g = b & 7, j = b >> 3;
    for (int c = threadIdx.x; c < NCOARSE; c += 256)
        H[(c * 8 + g) * 128 + j] = hist[c];
}

// ---- 3-kernel exclusive scan of H (400384 elems) -> goff, plus cbase[c] ----
__global__ __launch_bounds__(256) void scanA_k(const int* __restrict__ H,
                                               int* __restrict__ bsum) {
    __shared__ int sm[256];
    int i = blockIdx.x * 256 + threadIdx.x;
    sm[threadIdx.x] = H[i];
    __syncthreads();
    for (int o = 128; o > 0; o >>= 1) {
        if (threadIdx.x < o) sm[threadIdx.x] += sm[threadIdx.x + o];
        __syncthreads();
    }
    if (threadIdx.x == 0) bsum[blockIdx.x] = sm[0];
}

__global__ __launch_bounds__(1024) void scanB_k(const int* __restrict__ bsum,
                                                int* __restrict__ boff) {
    __shared__ int tsum[1024];
    int t = threadIdx.x;
    int v[2], s = 0;
#pragma unroll
    for (int j = 0; j < 2; ++j) {
        int idx = t * 2 + j;
        v[j] = (idx < NSCN) ? bsum[idx] : 0;
        s += v[j];
    }
    tsum[t] = s;
    __syncthreads();
    for (int o = 1; o < 1024; o <<= 1) {
        int add = (t >= o) ? tsum[t - o] : 0;
        __syncthreads();
        tsum[t] += add;
        __syncthreads();
    }
    int excl = tsum[t] - s;
#pragma unroll
    for (int j = 0; j < 2; ++j) {
        int idx = t * 2 + j;
        if (idx < NSCN) { boff[idx] = excl; excl += v[j]; }
    }
}

__global__ __launch_bounds__(256) void scanC_k(const int* __restrict__ H,
                                               const int* __restrict__ boff,
                                               int* __restrict__ goff,
                                               int* __restrict__ cbase) {
    __shared__ int sm[256];
    int blk = blockIdx.x, t = threadIdx.x;
    int i = blk * 256 + t;
    int v = H[i];
    sm[t] = v;
    __syncthreads();
    for (int o = 1; o < 256; o <<= 1) {
        int add = (t >= o) ? sm[t - o] : 0;
        __syncthreads();
        sm[t] += add;
        __syncthreads();
    }
    int excl = boff[blk] + sm[t] - v;
    goff[i] = excl;
    if ((i & 1023) == 0) cbase[i >> 10] = excl;  // start of bucket c = i/1024
    if (i == 0) cbase[NCOARSE] = N_EDGES;
}

// coarse scatter, deterministic: LDS cursors preloaded from goff; NO global atomics
__global__ __launch_bounds__(256) void coarse_scatter_k(const int* __restrict__ src,
                                                        const int* __restrict__ dst,
                                                        const int* __restrict__ goff,
                                                        int* __restrict__ eC) {
    __shared__ int cur[NCOARSE];
    int b = blockIdx.x, t = threadIdx.x, g = b & 7, j = b >> 3;
    for (int c = t; c < NCOARSE; c += 256)
        cur[c] = goff[(c * 8 + g) * 128 + j];
    __syncthreads();
    int e0 = b * EPB, e1 = min(e0 + EPB, N_EDGES);
    for (int e = e0 + t; e < e1; e += 256) {
        int s = src[e], d = dst[e];
        int pos = atomicAdd(&cur[d >> 8], 1);  // LDS atomic
        eC[pos] = s | ((d & 255) << 17);
    }
}

// per bucket: node counts (LDS) -> rowptr + dinv
__global__ __launch_bounds__(256) void bucket_count_k(const int* __restrict__ eC,
                                                      const int* __restrict__ cbase,
                                                      int* __restrict__ rowptr,
                                                      float* __restrict__ dinv) {
    __shared__ int cnt[256];
    __shared__ int sc[256];
    int c = blockIdx.x, t = threadIdx.x;
    cnt[t] = 0;
    __syncthreads();
    int s0 = cbase[c], s1 = cbase[c + 1];
    for (int e = s0 + t; e < s1; e += 256)
        atomicAdd(&cnt[(eC[e] >> 17) & 255], 1);
    __syncthreads();
    int v = cnt[t];
    sc[t] = v;
    __syncthreads();
    for (int o = 1; o < 256; o <<= 1) {
        int add = (t >= o) ? sc[t - o] : 0;
        __syncthreads();
        sc[t] += add;
        __syncthreads();
    }
    int node = c * 256 + t;
    if (node < N_NODES) {
        rowptr[node] = s0 + sc[t] - v;
        dinv[node] = rsqrtf((float)v + 1.0f);  // +1 self loop
    }
    if (node == N_NODES - 1) rowptr[N_NODES] = s1;
}

// per bucket: final scatter with norm; block-exclusive output region
__global__ __launch_bounds__(256) void bucket_scatter_k(const int* __restrict__ eC,
                                                        const int* __restrict__ cbase,
                                                        const int* __restrict__ rowptr,
                                                        const float* __restrict__ dinv,
                                                        int2* __restrict__ epack) {
    __shared__ int cur[256];
    __shared__ float dv[256];
    int c = blockIdx.x, t = threadIdx.x;
    int node = c * 256 + t;
    cur[t] = (node < N_NODES) ? rowptr[node] : 0;
    dv[t] = (node < N_NODES) ? dinv[node] : 0.0f;
    __syncthreads();
    int s0 = cbase[c], s1 = cbase[c + 1];
    for (int e = s0 + t; e < s1; e += 256) {
        int u = eC[e];
        int s = u & 0x1FFFF;
        int doff = (u >> 17) & 255;
        float nm = dinv[s] * dv[doff];
        int pos = atomicAdd(&cur[doff], 1);
        epack[pos] = make_int2(s, __float_as_int(nm));
    }
}

// ---------------------------------------------------------------------------
// GEMM: W staged in LDS; A fp32 from global; OUT fp16. 2 rows x 8 cols/thread.
#define FMA8(av, wl, wh, accrow)                       \
    accrow[0] = fmaf(av, wl.x, accrow[0]);             \
    accrow[1] = fmaf(av, wl.y, accrow[1]);             \
    accrow[2] = fmaf(av, wl.z, accrow[2]);             \
    accrow[3] = fmaf(av, wl.w, accrow[3]);             \
    accrow[4] = fmaf(av, wh.x, accrow[4]);             \
    accrow[5] = fmaf(av, wh.y, accrow[5]);             \
    accrow[6] = fmaf(av, wh.z, accrow[6]);             \
    accrow[7] = fmaf(av, wh.w, accrow[7]);

template <int K>
__global__ __launch_bounds__(256) void gemm_k(const float* __restrict__ A,
                                              const float* __restrict__ W,
                                              __half* __restrict__ out) {
    __shared__ float Wl[K * 64];
    for (int i = threadIdx.x * 4; i < K * 64; i += 1024)
        *(float4*)&Wl[i] = *(const float4*)&W[i];
    __syncthreads();

    const int tx = threadIdx.x & 7;
    const int ty = threadIdx.x >> 3;   // 0..31
    const int c0 = tx * 8;
    const int r0 = blockIdx.x * 64 + ty * 2;
    float acc[2][8];
#pragma unroll
    for (int i = 0; i < 2; ++i)
#pragma unroll
        for (int j = 0; j < 8; ++j) acc[i][j] = 0.0f;

#pragma unroll 2
    for (int kc = 0; kc < K; kc += 4) {
        float4 a[2];
#pragma unroll
        for (int i = 0; i < 2; ++i) {
            int r = r0 + i;
            a[i] = (r < N_NODES) ? *(const float4*)(A + (size_t)r * K + kc)
                                 : make_float4(0.f, 0.f, 0.f, 0.f);
        }
        float4 wlo[4], whi[4];
#pragma unroll
        for (int j = 0; j < 4; ++j) {
            wlo[j] = *(const float4*)&Wl[(kc + j) * HDIM + c0];
            whi[j] = *(const float4*)&Wl[(kc + j) * HDIM + c0 + 4];
        }
#pragma unroll
        for (int i = 0; i < 2; ++i) {
            FMA8(a[i].x, wlo[0], whi[0], acc[i]);
            FMA8(a[i].y, wlo[1], whi[1], acc[i]);
            FMA8(a[i].z, wlo[2], whi[2], acc[i]);
            FMA8(a[i].w, wlo[3], whi[3], acc[i]);
        }
    }
#pragma unroll
    for (int i = 0; i < 2; ++i) {
        int r = r0 + i;
        if (r < N_NODES) {
            __half hb[8];
#pragma unroll
            for (int j = 0; j < 8; ++j) hb[j] = __float2half(acc[i][j]);
            *(uint4*)(out + (size_t)r * HDIM + c0) = *(uint4*)hb;  // 16B store
        }
    }
}

// ---------------------------------------------------------------------------
// one wave per dst node; wave-uniform int4 metadata loads, 8 fp16 gathers
// (128B/row) in flight; fp32 accumulate; fp32 store.
template <bool RELU_OUT>
__global__ __launch_bounds__(256) void agg_k(const int* __restrict__ rowptr,
                                             const int2* __restrict__ epack,
                                             const float* __restrict__ dinv,
                                             const __half* __restrict__ hw,
                                             const float* __restrict__ b,
                                             float* __restrict__ h) {
    const int lane = threadIdx.x & 63;
    int node = (blockIdx.x * 256 + threadIdx.x) >> 6;
    if (node >= N_NODES) return;
    int e0 = rowptr[node], e1 = rowptr[node + 1];
    float dv = dinv[node];
    float acc = b[lane] + __half2float(hw[(size_t)node * HDIM + lane]) * dv * dv;

    int e = e0;
    if ((e & 1) && e < e1) {
        int2 m = epack[e];
        acc = fmaf(__half2float(hw[(size_t)m.x * HDIM + lane]),
                   __int_as_float(m.y), acc);
        ++e;
    }
    for (; e + 8 <= e1; e += 8) {
        int4 m0 = *(const int4*)(epack + e);
        int4 m1 = *(const int4*)(epack + e + 2);
        int4 m2 = *(const int4*)(epack + e + 4);
        int4 m3 = *(const int4*)(epack + e + 6);
        float v0 = __half2float(hw[(size_t)m0.x * HDIM + lane]);
        float v1 = __half2float(hw[(size_t)m0.z * HDIM + lane]);
        float v2 = __half2float(hw[(size_t)m1.x * HDIM + lane]);
        float v3 = __half2float(hw[(size_t)m1.z * HDIM + lane]);
        float v4 = __half2float(hw[(size_t)m2.x * HDIM + lane]);
        float v5 = __half2float(hw[(size_t)m2.z * HDIM + lane]);
        float v6 = __half2float(hw[(size_t)m3.x * HDIM + lane]);
        float v7 = __half2float(hw[(size_t)m3.z * HDIM + lane]);
        acc = fmaf(v0, __int_as_float(m0.y), acc);
        acc = fmaf(v1, __int_as_float(m0.w), acc);
        acc = fmaf(v2, __int_as_float(m1.y), acc);
        acc = fmaf(v3, __int_as_float(m1.w), acc);
        acc = fmaf(v4, __int_as_float(m2.y), acc);
        acc = fmaf(v5, __int_as_float(m2.w), acc);
        acc = fmaf(v6, __int_as_float(m3.y), acc);
        acc = fmaf(v7, __int_as_float(m3.w), acc);
    }
    for (; e < e1; ++e) {
        int2 m = epack[e];
        acc = fmaf(__half2float(hw[(size_t)m.x * HDIM + lane]),
                   __int_as_float(m.y), acc);
    }
    if (RELU_OUT) acc = fmaxf(acc, 0.0f);
    h[(size_t)node * HDIM + lane] = acc;
}

// ---------------------------------------------------------------------------
__global__ __launch_bounds__(256) void pool_k(const float* __restrict__ h,
                                              const int* __restrict__ batch,
                                              const float* __restrict__ lw,
                                              float* __restrict__ gsum,
                                              float* __restrict__ gcnt) {
    int i = blockIdx.x * blockDim.x + threadIdx.x;
    bool act = i < N_NODES;
    float dot = 0.0f;
    int g = -1;
    if (act) {
        g = batch[i];
        const float4* row = (const float4*)(h + (size_t)i * HDIM);
        const float4* w4  = (const float4*)lw;
#pragma unroll
        for (int q = 0; q < 16; ++q) {
            float4 v = row[q], w = w4[q];
            dot = fmaf(v.x, w.x, dot);
            dot = fmaf(v.y, w.y, dot);
            dot = fmaf(v.z, w.z, dot);
            dot = fmaf(v.w, w.w, dot);
        }
    }
    int g0 = __shfl(g, 0);
    bool uni = (__ballot(act && (g == g0)) == ~0ULL);
    if (uni) {
        for (int o = 32; o > 0; o >>= 1) dot += __shfl_down(dot, o);
        if ((threadIdx.x & 63) == 0) {
            atomicAdd(&gsum[g0], dot);
            atomicAdd(&gcnt[g0], 64.0f);
        }
    } else if (act) {
        atomicAdd(&gsum[g], dot);
        atomicAdd(&gcnt[g], 1.0f);
    }
}

__global__ void final_k(float* __restrict__ out, const float* __restrict__ gsum,
                        const float* __restrict__ gcnt, const float* __restrict__ lb) {
    int g = blockIdx.x * blockDim.x + threadIdx.x;
    if (g < N_GRAPHS) out[g] = gsum[g] / fmaxf(gcnt[g], 1.0f) + lb[0];
}

// ---------------------------------------------------------------------------
extern "C" void kernel_launch(void* const* d_in, const int* in_sizes, int n_in,
                              void* d_out, int out_size, void* d_ws, size_t ws_size,
                              hipStream_t stream) {
    const float* x     = (const float*)d_in[0];
    const int*   eidx  = (const int*)d_in[1];   // [2, E] int32
    const int*   batch = (const int*)d_in[3];
    const float* W1 = (const float*)d_in[4];
    const float* b1 = (const float*)d_in[5];
    const float* W2 = (const float*)d_in[6];
    const float* b2 = (const float*)d_in[7];
    const float* W3 = (const float*)d_in[8];
    const float* b3 = (const float*)d_in[9];
    const float* lin_w = (const float*)d_in[10];
    const float* lin_b = (const float*)d_in[11];
    float* out = (float*)d_out;

    const int* src = eidx;
    const int* dst = eidx + N_EDGES;

    float*  ws     = (float*)d_ws;
    float*  dinv   = ws;                         // 100352 f
    int*    rowptr = (int*)(ws + 100352);        // 100352 i (needs 100001)
    int*    cbase  = rowptr + 100352;            // 512 (needs 392)
    int*    bsum   = cbase + 512;                // 1600 (needs 1564)
    int*    boff   = bsum + 1600;                // 1600
    int*    H      = boff + 1600;                // 400384
    int*    goff   = H + 400384;                 // 400384
    int2*   epack  = (int2*)(goff + 400384);     // 1.6M int2; offset 605184*4B %16==0
    __half* bufH   = (__half*)(epack + N_EDGES); // 6.4M halfs (12.8 MB) gemm-out
    float*  bufF   = (float*)(bufH + 6400000);   // 6.4M f (25.6 MB) agg-out
    float*  gsum   = bufF + 6400000;             // 1024
    float*  gcnt   = gsum + 1024;                // 1024   (~54 MB total)
    int*    eC     = (int*)bufH;                 // 1.6M i, aliases bufH (dead before gemm1)

    // ---- CSR build (deterministic; zero global atomics) ----
    zero_k<<<4, 256, 0, stream>>>(gsum, gcnt);
    coarse_hist_k<<<NBLK_AB, 256, 0, stream>>>(dst, H);
    scanA_k<<<NSCN, 256, 0, stream>>>(H, bsum);
    scanB_k<<<1, 1024, 0, stream>>>(bsum, boff);
    scanC_k<<<NSCN, 256, 0, stream>>>(H, boff, goff, cbase);
    coarse_scatter_k<<<NBLK_AB, 256, 0, stream>>>(src, dst, goff, eC);
    bucket_count_k<<<NCOARSE, 256, 0, stream>>>(eC, cbase, rowptr, dinv);
    bucket_scatter_k<<<NCOARSE, 256, 0, stream>>>(eC, cbase, rowptr, dinv, epack);

    // ---- 3 GCN layers (relu folded into agg store) ----
    gemm_k<F_IN><<<1563, 256, 0, stream>>>(x, W1, bufH);
    agg_k<true><<<25000, 256, 0, stream>>>(rowptr, epack, dinv, bufH, b1, bufF);

    gemm_k<HDIM><<<1563, 256, 0, stream>>>(bufF, W2, bufH);
    agg_k<true><<<25000, 256, 0, stream>>>(rowptr, epack, dinv, bufH, b2, bufF);

    gemm_k<HDIM><<<1563, 256, 0, stream>>>(bufF, W3, bufH);
    agg_k<false><<<25000, 256, 0, stream>>>(rowptr, epack, dinv, bufH, b3, bufF);

    // ---- pool + head ----
    pool_k<<<(N_NODES + 255) / 256, 256, 0, stream>>>(bufF, batch, lin_w, gsum, gcnt);
    final_k<<<(N_GRAPHS + 255) / 256, 256, 0, stream>>>(out, gsum, gcnt, lin_b);
}

// Round 10
// 494.390 us; speedup vs baseline: 1.5498x; 1.0590x over previous
//
#include <hip/hip_runtime.h>
#include <hip/hip_fp16.h>

#define N_NODES 100000
#define N_EDGES 1600000
#define N_GRAPHS 1024
#define F_IN 128
#define HDIM 64
#define NCOARSE 391            // dst>>8 buckets
#define NBLK_AB 1024
#define EPB 1563               // ceil(N_EDGES / NBLK_AB)
#define NH (NCOARSE * 8 * 128) // 400384 = per-(bucket,g,j) histogram
#define NSCN (NH / 256)        // 1564 scan blocks

typedef _Float16 half4f __attribute__((ext_vector_type(4)));
typedef float f32x4 __attribute__((ext_vector_type(4)));

// ---------------------------------------------------------------------------
__global__ void zero_k(float* __restrict__ gsum, float* __restrict__ gcnt) {
    int i = blockIdx.x * blockDim.x + threadIdx.x;
    if (i < N_GRAPHS) { gsum[i] = 0.0f; gcnt[i] = 0.0f; }
}

// per-block LDS coarse histogram -> H[(c*8+g)*128+j], g=b&7, j=b>>3
__global__ __launch_bounds__(256) void coarse_hist_k(const int* __restrict__ dst,
                                                     int* __restrict__ H) {
    __shared__ int hist[NCOARSE];
    for (int i = threadIdx.x; i < NCOARSE; i += 256) hist[i] = 0;
    __syncthreads();
    int b = blockIdx.x;
    int e0 = b * EPB, e1 = min(e0 + EPB, N_EDGES);
    for (int e = e0 + threadIdx.x; e < e1; e += 256)
        atomicAdd(&hist[dst[e] >> 8], 1);
    __syncthreads();
    int g = b & 7, j = b >> 3;
    for (int c = threadIdx.x; c < NCOARSE; c += 256)
        H[(c * 8 + g) * 128 + j] = hist[c];
}

// ---- 3-kernel exclusive scan of H (400384 elems) -> goff, plus cbase[c] ----
__global__ __launch_bounds__(256) void scanA_k(const int* __restrict__ H,
                                               int* __restrict__ bsum) {
    __shared__ int sm[256];
    int i = blockIdx.x * 256 + threadIdx.x;
    sm[threadIdx.x] = H[i];
    __syncthreads();
    for (int o = 128; o > 0; o >>= 1) {
        if (threadIdx.x < o) sm[threadIdx.x] += sm[threadIdx.x + o];
        __syncthreads();
    }
    if (threadIdx.x == 0) bsum[blockIdx.x] = sm[0];
}

__global__ __launch_bounds__(1024) void scanB_k(const int* __restrict__ bsum,
                                                int* __restrict__ boff) {
    __shared__ int tsum[1024];
    int t = threadIdx.x;
    int v[2], s = 0;
#pragma unroll
    for (int j = 0; j < 2; ++j) {
        int idx = t * 2 + j;
        v[j] = (idx < NSCN) ? bsum[idx] : 0;
        s += v[j];
    }
    tsum[t] = s;
    __syncthreads();
    for (int o = 1; o < 1024; o <<= 1) {
        int add = (t >= o) ? tsum[t - o] : 0;
        __syncthreads();
        tsum[t] += add;
        __syncthreads();
    }
    int excl = tsum[t] - s;
#pragma unroll
    for (int j = 0; j < 2; ++j) {
        int idx = t * 2 + j;
        if (idx < NSCN) { boff[idx] = excl; excl += v[j]; }
    }
}

__global__ __launch_bounds__(256) void scanC_k(const int* __restrict__ H,
                                               const int* __restrict__ boff,
                                               int* __restrict__ goff,
                                               int* __restrict__ cbase) {
    __shared__ int sm[256];
    int blk = blockIdx.x, t = threadIdx.x;
    int i = blk * 256 + t;
    int v = H[i];
    sm[t] = v;
    __syncthreads();
    for (int o = 1; o < 256; o <<= 1) {
        int add = (t >= o) ? sm[t - o] : 0;
        __syncthreads();
        sm[t] += add;
        __syncthreads();
    }
    int excl = boff[blk] + sm[t] - v;
    goff[i] = excl;
    if ((i & 1023) == 0) cbase[i >> 10] = excl;  // start of bucket c = i/1024
    if (i == 0) cbase[NCOARSE] = N_EDGES;
}

// coarse scatter, deterministic: LDS cursors preloaded from goff; NO global atomics
__global__ __launch_bounds__(256) void coarse_scatter_k(const int* __restrict__ src,
                                                        const int* __restrict__ dst,
                                                        const int* __restrict__ goff,
                                                        int* __restrict__ eC) {
    __shared__ int cur[NCOARSE];
    int b = blockIdx.x, t = threadIdx.x, g = b & 7, j = b >> 3;
    for (int c = t; c < NCOARSE; c += 256)
        cur[c] = goff[(c * 8 + g) * 128 + j];
    __syncthreads();
    int e0 = b * EPB, e1 = min(e0 + EPB, N_EDGES);
    for (int e = e0 + t; e < e1; e += 256) {
        int s = src[e], d = dst[e];
        int pos = atomicAdd(&cur[d >> 8], 1);  // LDS atomic
        eC[pos] = s | ((d & 255) << 17);
    }
}

// per bucket: node counts (LDS) -> rowptr + dinv
__global__ __launch_bounds__(256) void bucket_count_k(const int* __restrict__ eC,
                                                      const int* __restrict__ cbase,
                                                      int* __restrict__ rowptr,
                                                      float* __restrict__ dinv) {
    __shared__ int cnt[256];
    __shared__ int sc[256];
    int c = blockIdx.x, t = threadIdx.x;
    cnt[t] = 0;
    __syncthreads();
    int s0 = cbase[c], s1 = cbase[c + 1];
    for (int e = s0 + t; e < s1; e += 256)
        atomicAdd(&cnt[(eC[e] >> 17) & 255], 1);
    __syncthreads();
    int v = cnt[t];
    sc[t] = v;
    __syncthreads();
    for (int o = 1; o < 256; o <<= 1) {
        int add = (t >= o) ? sc[t - o] : 0;
        __syncthreads();
        sc[t] += add;
        __syncthreads();
    }
    int node = c * 256 + t;
    if (node < N_NODES) {
        rowptr[node] = s0 + sc[t] - v;
        dinv[node] = rsqrtf((float)v + 1.0f);  // +1 self loop
    }
    if (node == N_NODES - 1) rowptr[N_NODES] = s1;
}

// per bucket: final scatter with norm; block-exclusive output region
__global__ __launch_bounds__(256) void bucket_scatter_k(const int* __restrict__ eC,
                                                        const int* __restrict__ cbase,
                                                        const int* __restrict__ rowptr,
                                                        const float* __restrict__ dinv,
                                                        int2* __restrict__ epack) {
    __shared__ int cur[256];
    __shared__ float dv[256];
    int c = blockIdx.x, t = threadIdx.x;
    int node = c * 256 + t;
    cur[t] = (node < N_NODES) ? rowptr[node] : 0;
    dv[t] = (node < N_NODES) ? dinv[node] : 0.0f;
    __syncthreads();
    int s0 = cbase[c], s1 = cbase[c + 1];
    for (int e = s0 + t; e < s1; e += 256) {
        int u = eC[e];
        int s = u & 0x1FFFF;
        int doff = (u >> 17) & 255;
        float nm = dinv[s] * dv[doff];
        int pos = atomicAdd(&cur[doff], 1);
        epack[pos] = make_int2(s, __float_as_int(nm));
    }
}

// ---------------------------------------------------------------------------
// MFMA GEMM: out[r][c] = sum_k A[r][k] * W[k][c], A fp32->fp16 in-register,
// W fp32 -> fp16 transposed in LDS, v_mfma_f32_16x16x16_f16, fp32 accum,
// fp16 out. Block: 256 thr = 4 waves; 64-row M-tile; wave w owns cols 16w..16w+15.
// Layouts (CDNA3-documented, m89-consistent):
//   A-frag: row = lane&15, k = kbase + (lane>>4)*4 + j
//   B-frag: col = lane&15, k = same
//   D:      col = lane&15, row = (lane>>4)*4 + reg
template <int K>
__global__ __launch_bounds__(256) void gemm_k(const float* __restrict__ A,
                                              const float* __restrict__ W,
                                              __half* __restrict__ out) {
    constexpr int PITCH = K + 24;  // halves; 2B*PITCH % 16 == 0, bank stride 12
    __shared__ __align__(16) _Float16 Wt[64 * PITCH];
    for (int i = threadIdx.x; i < K * 64; i += 256) {
        int k = i >> 6, c = i & 63;
        Wt[c * PITCH + k] = (_Float16)W[i];
    }
    __syncthreads();

    const int lane = threadIdx.x & 63;
    const int wid  = threadIdx.x >> 6;   // 0..3 -> col tile
    const int cl   = lane & 15;
    const int kq   = lane >> 4;          // 0..3
    const int c0   = wid * 16;
    const int r0   = blockIdx.x * 64;

    f32x4 acc[4] = {};
#pragma unroll
    for (int ks = 0; ks < K / 16; ++ks) {
        const int kbase = ks * 16 + kq * 4;
        const half4f bf = *(const half4f*)&Wt[(c0 + cl) * PITCH + kbase];
#pragma unroll
        for (int m = 0; m < 4; ++m) {
            int r = r0 + m * 16 + cl;
            float4 a4 = (r < N_NODES)
                            ? *(const float4*)(A + (size_t)r * K + kbase)
                            : make_float4(0.f, 0.f, 0.f, 0.f);
            half4f af = {(_Float16)a4.x, (_Float16)a4.y,
                         (_Float16)a4.z, (_Float16)a4.w};
            acc[m] = __builtin_amdgcn_mfma_f32_16x16x16f16(af, bf, acc[m], 0, 0, 0);
        }
    }
#pragma unroll
    for (int m = 0; m < 4; ++m) {
        int rbase = r0 + m * 16 + kq * 4;
#pragma unroll
        for (int reg = 0; reg < 4; ++reg) {
            int r = rbase + reg;
            if (r < N_NODES)
                out[(size_t)r * HDIM + c0 + cl] = __float2half(acc[m][reg]);
        }
    }
}

// ---------------------------------------------------------------------------
// one wave per dst node; wave-uniform int4 metadata loads, 8 fp16 gathers
// (128B/row) in flight; fp32 accumulate; fp32 store.
template <bool RELU_OUT>
__global__ __launch_bounds__(256) void agg_k(const int* __restrict__ rowptr,
                                             const int2* __restrict__ epack,
                                             const float* __restrict__ dinv,
                                             const __half* __restrict__ hw,
                                             const float* __restrict__ b,
                                             float* __restrict__ h) {
    const int lane = threadIdx.x & 63;
    int node = (blockIdx.x * 256 + threadIdx.x) >> 6;
    if (node >= N_NODES) return;
    int e0 = rowptr[node], e1 = rowptr[node + 1];
    float dv = dinv[node];
    float acc = b[lane] + __half2float(hw[(size_t)node * HDIM + lane]) * dv * dv;

    int e = e0;
    if ((e & 1) && e < e1) {
        int2 m = epack[e];
        acc = fmaf(__half2float(hw[(size_t)m.x * HDIM + lane]),
                   __int_as_float(m.y), acc);
        ++e;
    }
    for (; e + 8 <= e1; e += 8) {
        int4 m0 = *(const int4*)(epack + e);
        int4 m1 = *(const int4*)(epack + e + 2);
        int4 m2 = *(const int4*)(epack + e + 4);
        int4 m3 = *(const int4*)(epack + e + 6);
        float v0 = __half2float(hw[(size_t)m0.x * HDIM + lane]);
        float v1 = __half2float(hw[(size_t)m0.z * HDIM + lane]);
        float v2 = __half2float(hw[(size_t)m1.x * HDIM + lane]);
        float v3 = __half2float(hw[(size_t)m1.z * HDIM + lane]);
        float v4 = __half2float(hw[(size_t)m2.x * HDIM + lane]);
        float v5 = __half2float(hw[(size_t)m2.z * HDIM + lane]);
        float v6 = __half2float(hw[(size_t)m3.x * HDIM + lane]);
        float v7 = __half2float(hw[(size_t)m3.z * HDIM + lane]);
        acc = fmaf(v0, __int_as_float(m0.y), acc);
        acc = fmaf(v1, __int_as_float(m0.w), acc);
        acc = fmaf(v2, __int_as_float(m1.y), acc);
        acc = fmaf(v3, __int_as_float(m1.w), acc);
        acc = fmaf(v4, __int_as_float(m2.y), acc);
        acc = fmaf(v5, __int_as_float(m2.w), acc);
        acc = fmaf(v6, __int_as_float(m3.y), acc);
        acc = fmaf(v7, __int_as_float(m3.w), acc);
    }
    for (; e < e1; ++e) {
        int2 m = epack[e];
        acc = fmaf(__half2float(hw[(size_t)m.x * HDIM + lane]),
                   __int_as_float(m.y), acc);
    }
    if (RELU_OUT) acc = fmaxf(acc, 0.0f);
    h[(size_t)node * HDIM + lane] = acc;
}

// ---------------------------------------------------------------------------
__global__ __launch_bounds__(256) void pool_k(const float* __restrict__ h,
                                              const int* __restrict__ batch,
                                              const float* __restrict__ lw,
                                              float* __restrict__ gsum,
                                              float* __restrict__ gcnt) {
    int i = blockIdx.x * blockDim.x + threadIdx.x;
    bool act = i < N_NODES;
    float dot = 0.0f;
    int g = -1;
    if (act) {
        g = batch[i];
        const float4* row = (const float4*)(h + (size_t)i * HDIM);
        const float4* w4  = (const float4*)lw;
#pragma unroll
        for (int q = 0; q < 16; ++q) {
            float4 v = row[q], w = w4[q];
            dot = fmaf(v.x, w.x, dot);
            dot = fmaf(v.y, w.y, dot);
            dot = fmaf(v.z, w.z, dot);
            dot = fmaf(v.w, w.w, dot);
        }
    }
    int g0 = __shfl(g, 0);
    bool uni = (__ballot(act && (g == g0)) == ~0ULL);
    if (uni) {
        for (int o = 32; o > 0; o >>= 1) dot += __shfl_down(dot, o);
        if ((threadIdx.x & 63) == 0) {
            atomicAdd(&gsum[g0], dot);
            atomicAdd(&gcnt[g0], 64.0f);
        }
    } else if (act) {
        atomicAdd(&gsum[g], dot);
        atomicAdd(&gcnt[g], 1.0f);
    }
}

__global__ void final_k(float* __restrict__ out, const float* __restrict__ gsum,
                        const float* __restrict__ gcnt, const float* __restrict__ lb) {
    int g = blockIdx.x * blockDim.x + threadIdx.x;
    if (g < N_GRAPHS) out[g] = gsum[g] / fmaxf(gcnt[g], 1.0f) + lb[0];
}

// ---------------------------------------------------------------------------
extern "C" void kernel_launch(void* const* d_in, const int* in_sizes, int n_in,
                              void* d_out, int out_size, void* d_ws, size_t ws_size,
                              hipStream_t stream) {
    const float* x     = (const float*)d_in[0];
    const int*   eidx  = (const int*)d_in[1];   // [2, E] int32
    const int*   batch = (const int*)d_in[3];
    const float* W1 = (const float*)d_in[4];
    const float* b1 = (const float*)d_in[5];
    const float* W2 = (const float*)d_in[6];
    const float* b2 = (const float*)d_in[7];
    const float* W3 = (const float*)d_in[8];
    const float* b3 = (const float*)d_in[9];
    const float* lin_w = (const float*)d_in[10];
    const float* lin_b = (const float*)d_in[11];
    float* out = (float*)d_out;

    const int* src = eidx;
    const int* dst = eidx + N_EDGES;

    float*  ws     = (float*)d_ws;
    float*  dinv   = ws;                         // 100352 f
    int*    rowptr = (int*)(ws + 100352);        // 100352 i (needs 100001)
    int*    cbase  = rowptr + 100352;            // 512 (needs 392)
    int*    bsum   = cbase + 512;                // 1600 (needs 1564)
    int*    boff   = bsum + 1600;                // 1600
    int*    H      = boff + 1600;                // 400384
    int*    goff   = H + 400384;                 // 400384
    int2*   epack  = (int2*)(goff + 400384);     // 1.6M int2; 16B-aligned
    __half* bufH   = (__half*)(epack + N_EDGES); // 6.4M halfs (12.8 MB) gemm-out
    float*  bufF   = (float*)(bufH + 6400000);   // 6.4M f (25.6 MB) agg-out
    float*  gsum   = bufF + 6400000;             // 1024
    float*  gcnt   = gsum + 1024;                // 1024   (~54 MB total)
    int*    eC     = (int*)bufH;                 // 1.6M i, aliases bufH (dead before gemm1)

    // ---- CSR build (deterministic; zero global atomics) ----
    zero_k<<<4, 256, 0, stream>>>(gsum, gcnt);
    coarse_hist_k<<<NBLK_AB, 256, 0, stream>>>(dst, H);
    scanA_k<<<NSCN, 256, 0, stream>>>(H, bsum);
    scanB_k<<<1, 1024, 0, stream>>>(bsum, boff);
    scanC_k<<<NSCN, 256, 0, stream>>>(H, boff, goff, cbase);
    coarse_scatter_k<<<NBLK_AB, 256, 0, stream>>>(src, dst, goff, eC);
    bucket_count_k<<<NCOARSE, 256, 0, stream>>>(eC, cbase, rowptr, dinv);
    bucket_scatter_k<<<NCOARSE, 256, 0, stream>>>(eC, cbase, rowptr, dinv, epack);

    // ---- 3 GCN layers (relu folded into agg store) ----
    gemm_k<F_IN><<<1563, 256, 0, stream>>>(x, W1, bufH);
    agg_k<true><<<25000, 256, 0, stream>>>(rowptr, epack, dinv, bufH, b1, bufF);

    gemm_k<HDIM><<<1563, 256, 0, stream>>>(bufF, W2, bufH);
    agg_k<true><<<25000, 256, 0, stream>>>(rowptr, epack, dinv, bufH, b2, bufF);

    gemm_k<HDIM><<<1563, 256, 0, stream>>>(bufF, W3, bufH);
    agg_k<false><<<25000, 256, 0, stream>>>(rowptr, epack, dinv, bufH, b3, bufF);

    // ---- pool + head ----
    pool_k<<<(N_NODES + 255) / 256, 256, 0, stream>>>(bufF, batch, lin_w, gsum, gcnt);
    final_k<<<(N_GRAPHS + 255) / 256, 256, 0, stream>>>(out, gsum, gcnt, lin_b);
}

// Round 11
// 403.632 us; speedup vs baseline: 1.8983x; 1.2249x over previous
//
#include <hip/hip_runtime.h>
#include <hip/hip_fp16.h>

#define N_NODES 100000
#define N_EDGES 1600000
#define N_GRAPHS 1024
#define F_IN 128
#define HDIM 64
#define NCOARSE 391            // dst>>8 buckets
#define NBLK_AB 1024
#define EPB 1563               // ceil(N_EDGES / NBLK_AB)
#define NH (NCOARSE * 8 * 128) // 400384 = per-(bucket,g,j) histogram
#define NSCN (NH / 256)        // 1564 scan blocks

typedef _Float16 half4f __attribute__((ext_vector_type(4)));
typedef float f32x4 __attribute__((ext_vector_type(4)));

// ---------------------------------------------------------------------------
// block 0: wt = W3 @ lin_w (64), bconst = b3 . lin_w; blocks 1..4: zero gsum/gcnt
__global__ __launch_bounds__(256) void wtilde_k(const float* __restrict__ W3,
                                                const float* __restrict__ b3,
                                                const float* __restrict__ lw,
                                                float* __restrict__ wt,
                                                float* __restrict__ bc,
                                                float* __restrict__ gsum,
                                                float* __restrict__ gcnt) {
    if (blockIdx.x == 0) {
        int t = threadIdx.x;
        if (t < 64) {
            float d = 0.0f;
            for (int c = 0; c < 64; ++c) d = fmaf(W3[t * 64 + c], lw[c], d);
            wt[t] = d;
        } else if (t == 64) {
            float d = 0.0f;
            for (int c = 0; c < 64; ++c) d = fmaf(b3[c], lw[c], d);
            bc[0] = d;
        }
    } else {
        int i = (blockIdx.x - 1) * 256 + threadIdx.x;
        if (i < N_GRAPHS) { gsum[i] = 0.0f; gcnt[i] = 0.0f; }
    }
}

// per-block LDS coarse histogram -> H[(c*8+g)*128+j], g=b&7, j=b>>3
__global__ __launch_bounds__(256) void coarse_hist_k(const int* __restrict__ dst,
                                                     int* __restrict__ H) {
    __shared__ int hist[NCOARSE];
    for (int i = threadIdx.x; i < NCOARSE; i += 256) hist[i] = 0;
    __syncthreads();
    int b = blockIdx.x;
    int e0 = b * EPB, e1 = min(e0 + EPB, N_EDGES);
    for (int e = e0 + threadIdx.x; e < e1; e += 256)
        atomicAdd(&hist[dst[e] >> 8], 1);
    __syncthreads();
    int g = b & 7, j = b >> 3;
    for (int c = threadIdx.x; c < NCOARSE; c += 256)
        H[(c * 8 + g) * 128 + j] = hist[c];
}

// ---- 3-kernel exclusive scan of H (400384 elems) -> goff, plus cbase[c] ----
__global__ __launch_bounds__(256) void scanA_k(const int* __restrict__ H,
                                               int* __restrict__ bsum) {
    __shared__ int sm[256];
    int i = blockIdx.x * 256 + threadIdx.x;
    sm[threadIdx.x] = H[i];
    __syncthreads();
    for (int o = 128; o > 0; o >>= 1) {
        if (threadIdx.x < o) sm[threadIdx.x] += sm[threadIdx.x + o];
        __syncthreads();
    }
    if (threadIdx.x == 0) bsum[blockIdx.x] = sm[0];
}

__global__ __launch_bounds__(1024) void scanB_k(const int* __restrict__ bsum,
                                                int* __restrict__ boff) {
    __shared__ int tsum[1024];
    int t = threadIdx.x;
    int v[2], s = 0;
#pragma unroll
    for (int j = 0; j < 2; ++j) {
        int idx = t * 2 + j;
        v[j] = (idx < NSCN) ? bsum[idx] : 0;
        s += v[j];
    }
    tsum[t] = s;
    __syncthreads();
    for (int o = 1; o < 1024; o <<= 1) {
        int add = (t >= o) ? tsum[t - o] : 0;
        __syncthreads();
        tsum[t] += add;
        __syncthreads();
    }
    int excl = tsum[t] - s;
#pragma unroll
    for (int j = 0; j < 2; ++j) {
        int idx = t * 2 + j;
        if (idx < NSCN) { boff[idx] = excl; excl += v[j]; }
    }
}

__global__ __launch_bounds__(256) void scanC_k(const int* __restrict__ H,
                                               const int* __restrict__ boff,
                                               int* __restrict__ goff,
                                               int* __restrict__ cbase) {
    __shared__ int sm[256];
    int blk = blockIdx.x, t = threadIdx.x;
    int i = blk * 256 + t;
    int v = H[i];
    sm[t] = v;
    __syncthreads();
    for (int o = 1; o < 256; o <<= 1) {
        int add = (t >= o) ? sm[t - o] : 0;
        __syncthreads();
        sm[t] += add;
        __syncthreads();
    }
    int excl = boff[blk] + sm[t] - v;
    goff[i] = excl;
    if ((i & 1023) == 0) cbase[i >> 10] = excl;  // start of bucket c = i/1024
    if (i == 0) cbase[NCOARSE] = N_EDGES;
}

// coarse scatter, deterministic: LDS cursors preloaded from goff; NO global atomics
__global__ __launch_bounds__(256) void coarse_scatter_k(const int* __restrict__ src,
                                                        const int* __restrict__ dst,
                                                        const int* __restrict__ goff,
                                                        int* __restrict__ eC) {
    __shared__ int cur[NCOARSE];
    int b = blockIdx.x, t = threadIdx.x, g = b & 7, j = b >> 3;
    for (int c = t; c < NCOARSE; c += 256)
        cur[c] = goff[(c * 8 + g) * 128 + j];
    __syncthreads();
    int e0 = b * EPB, e1 = min(e0 + EPB, N_EDGES);
    for (int e = e0 + t; e < e1; e += 256) {
        int s = src[e], d = dst[e];
        int pos = atomicAdd(&cur[d >> 8], 1);  // LDS atomic
        eC[pos] = s | ((d & 255) << 17);
    }
}

// per bucket: node counts (LDS) -> rowptr + dinv   (1024 thr: 24 waves/CU)
__global__ __launch_bounds__(1024) void bucket_count_k(const int* __restrict__ eC,
                                                       const int* __restrict__ cbase,
                                                       int* __restrict__ rowptr,
                                                       float* __restrict__ dinv) {
    __shared__ int cnt[256];
    __shared__ int sc[256];
    int c = blockIdx.x, t = threadIdx.x;
    if (t < 256) cnt[t] = 0;
    __syncthreads();
    int s0 = cbase[c], s1 = cbase[c + 1];
    for (int e = s0 + t; e < s1; e += 1024)
        atomicAdd(&cnt[(eC[e] >> 17) & 255], 1);
    __syncthreads();
    if (t < 256) sc[t] = cnt[t];
    __syncthreads();
    for (int o = 1; o < 256; o <<= 1) {
        int add = (t >= o && t < 256) ? sc[t - o] : 0;
        __syncthreads();
        if (t < 256) sc[t] += add;
        __syncthreads();
    }
    int node = c * 256 + t;
    if (t < 256 && node < N_NODES) {
        rowptr[node] = s0 + sc[t] - cnt[t];
        dinv[node] = rsqrtf((float)cnt[t] + 1.0f);  // +1 self loop
    }
    if (node == N_NODES - 1) rowptr[N_NODES] = s1;
}

// per bucket: final scatter with norm; block-exclusive output region (1024 thr)
__global__ __launch_bounds__(1024) void bucket_scatter_k(const int* __restrict__ eC,
                                                         const int* __restrict__ cbase,
                                                         const int* __restrict__ rowptr,
                                                         const float* __restrict__ dinv,
                                                         int2* __restrict__ epack) {
    __shared__ int cur[256];
    __shared__ float dv[256];
    int c = blockIdx.x, t = threadIdx.x;
    int node = c * 256 + t;
    if (t < 256) {
        cur[t] = (node < N_NODES) ? rowptr[node] : 0;
        dv[t] = (node < N_NODES) ? dinv[node] : 0.0f;
    }
    __syncthreads();
    int s0 = cbase[c], s1 = cbase[c + 1];
    for (int e = s0 + t; e < s1; e += 1024) {
        int u = eC[e];
        int s = u & 0x1FFFF;
        int doff = (u >> 17) & 255;
        float nm = dinv[s] * dv[doff];
        int pos = atomicAdd(&cur[doff], 1);
        epack[pos] = make_int2(s, __float_as_int(nm));
    }
}

// ---------------------------------------------------------------------------
// MFMA GEMM: out[r][c] = sum_k A[r][k]*W[k][c]; fp16 in-register A, fp16 Wt in
// LDS, v_mfma_f32_16x16x16_f16, fp32 accum, fp16 out.
template <int K>
__global__ __launch_bounds__(256) void gemm_k(const float* __restrict__ A,
                                              const float* __restrict__ W,
                                              __half* __restrict__ out) {
    constexpr int PITCH = K + 24;
    __shared__ __align__(16) _Float16 Wt[64 * PITCH];
    for (int i = threadIdx.x; i < K * 64; i += 256) {
        int k = i >> 6, c = i & 63;
        Wt[c * PITCH + k] = (_Float16)W[i];
    }
    __syncthreads();

    const int lane = threadIdx.x & 63;
    const int wid  = threadIdx.x >> 6;
    const int cl   = lane & 15;
    const int kq   = lane >> 4;
    const int c0   = wid * 16;
    const int r0   = blockIdx.x * 64;

    f32x4 acc[4] = {};
#pragma unroll
    for (int ks = 0; ks < K / 16; ++ks) {
        const int kbase = ks * 16 + kq * 4;
        const half4f bf = *(const half4f*)&Wt[(c0 + cl) * PITCH + kbase];
#pragma unroll
        for (int m = 0; m < 4; ++m) {
            int r = r0 + m * 16 + cl;
            float4 a4 = (r < N_NODES)
                            ? *(const float4*)(A + (size_t)r * K + kbase)
                            : make_float4(0.f, 0.f, 0.f, 0.f);
            half4f af = {(_Float16)a4.x, (_Float16)a4.y,
                         (_Float16)a4.z, (_Float16)a4.w};
            acc[m] = __builtin_amdgcn_mfma_f32_16x16x16f16(af, bf, acc[m], 0, 0, 0);
        }
    }
#pragma unroll
    for (int m = 0; m < 4; ++m) {
        int rbase = r0 + m * 16 + kq * 4;
#pragma unroll
        for (int reg = 0; reg < 4; ++reg) {
            int r = rbase + reg;
            if (r < N_NODES)
                out[(size_t)r * HDIM + c0 + cl] = __float2half(acc[m][reg]);
        }
    }
}

// ---------------------------------------------------------------------------
// one wave per dst node; wave-uniform int4 metadata loads, 8 fp16 gathers in
// flight; fp32 accumulate; relu'd fp32 store.
template <bool RELU_OUT>
__global__ __launch_bounds__(256) void agg_k(const int* __restrict__ rowptr,
                                             const int2* __restrict__ epack,
                                             const float* __restrict__ dinv,
                                             const __half* __restrict__ hw,
                                             const float* __restrict__ b,
                                             float* __restrict__ h) {
    const int lane = threadIdx.x & 63;
    int node = (blockIdx.x * 256 + threadIdx.x) >> 6;
    if (node >= N_NODES) return;
    int e0 = rowptr[node], e1 = rowptr[node + 1];
    float dv = dinv[node];
    float acc = b[lane] + __half2float(hw[(size_t)node * HDIM + lane]) * dv * dv;

    int e = e0;
    if ((e & 1) && e < e1) {
        int2 m = epack[e];
        acc = fmaf(__half2float(hw[(size_t)m.x * HDIM + lane]),
                   __int_as_float(m.y), acc);
        ++e;
    }
    for (; e + 8 <= e1; e += 8) {
        int4 m0 = *(const int4*)(epack + e);
        int4 m1 = *(const int4*)(epack + e + 2);
        int4 m2 = *(const int4*)(epack + e + 4);
        int4 m3 = *(const int4*)(epack + e + 6);
        float v0 = __half2float(hw[(size_t)m0.x * HDIM + lane]);
        float v1 = __half2float(hw[(size_t)m0.z * HDIM + lane]);
        float v2 = __half2float(hw[(size_t)m1.x * HDIM + lane]);
        float v3 = __half2float(hw[(size_t)m1.z * HDIM + lane]);
        float v4 = __half2float(hw[(size_t)m2.x * HDIM + lane]);
        float v5 = __half2float(hw[(size_t)m2.z * HDIM + lane]);
        float v6 = __half2float(hw[(size_t)m3.x * HDIM + lane]);
        float v7 = __half2float(hw[(size_t)m3.z * HDIM + lane]);
        acc = fmaf(v0, __int_as_float(m0.y), acc);
        acc = fmaf(v1, __int_as_float(m0.w), acc);
        acc = fmaf(v2, __int_as_float(m1.y), acc);
        acc = fmaf(v3, __int_as_float(m1.w), acc);
        acc = fmaf(v4, __int_as_float(m2.y), acc);
        acc = fmaf(v5, __int_as_float(m2.w), acc);
        acc = fmaf(v6, __int_as_float(m3.y), acc);
        acc = fmaf(v7, __int_as_float(m3.w), acc);
    }
    for (; e < e1; ++e) {
        int2 m = epack[e];
        acc = fmaf(__half2float(hw[(size_t)m.x * HDIM + lane]),
                   __int_as_float(m.y), acc);
    }
    if (RELU_OUT) acc = fmaxf(acc, 0.0f);
    h[(size_t)node * HDIM + lane] = acc;
}

// ---------------------------------------------------------------------------
// s[i] = h2r[i] . wt   (h2r = relu'd agg2 output, already relu'd in agg store)
__global__ __launch_bounds__(256) void s_k(const float* __restrict__ h2r,
                                           const float* __restrict__ wt,
                                           float* __restrict__ s) {
    __shared__ float wl[64];
    if (threadIdx.x < 64) wl[threadIdx.x] = wt[threadIdx.x];
    __syncthreads();
    int i = blockIdx.x * 256 + threadIdx.x;
    if (i >= N_NODES) return;
    const float4* row = (const float4*)(h2r + (size_t)i * HDIM);
    float dot = 0.0f;
#pragma unroll
    for (int q = 0; q < 16; ++q) {
        float4 v = row[q];
        dot = fmaf(v.x, wl[q * 4 + 0], dot);
        dot = fmaf(v.y, wl[q * 4 + 1], dot);
        dot = fmaf(v.z, wl[q * 4 + 2], dot);
        dot = fmaf(v.w, wl[q * 4 + 3], dot);
    }
    s[i] = dot;
}

// layer-3 scalar aggregation fused with graph mean-pool accumulation:
// nodeval_i = bconst + dinv_i^2 s[i] + sum_e norm_e s[src_e]
__global__ __launch_bounds__(256) void agg3s_k(const int* __restrict__ rowptr,
                                               const int2* __restrict__ epack,
                                               const float* __restrict__ dinv,
                                               const float* __restrict__ s,
                                               const int* __restrict__ batch,
                                               const float* __restrict__ bc,
                                               float* __restrict__ gsum,
                                               float* __restrict__ gcnt) {
    int i = blockIdx.x * 256 + threadIdx.x;
    bool act = i < N_NODES;
    float acc = 0.0f;
    int g = -1;
    if (act) {
        g = batch[i];
        float dv = dinv[i];
        acc = bc[0] + dv * dv * s[i];
        int e0 = rowptr[i], e1 = rowptr[i + 1];
        int e = e0;
        for (; e + 4 <= e1; e += 4) {
            int2 m0 = epack[e], m1 = epack[e + 1];
            int2 m2 = epack[e + 2], m3 = epack[e + 3];
            float t0 = s[m0.x], t1 = s[m1.x], t2 = s[m2.x], t3 = s[m3.x];
            acc = fmaf(t0, __int_as_float(m0.y), acc);
            acc = fmaf(t1, __int_as_float(m1.y), acc);
            acc = fmaf(t2, __int_as_float(m2.y), acc);
            acc = fmaf(t3, __int_as_float(m3.y), acc);
        }
        for (; e < e1; ++e) {
            int2 m = epack[e];
            acc = fmaf(s[m.x], __int_as_float(m.y), acc);
        }
    }
    int g0 = __shfl(g, 0);
    bool uni = (__ballot(act && (g == g0)) == ~0ULL);
    if (uni) {
        for (int o = 32; o > 0; o >>= 1) acc += __shfl_down(acc, o);
        if ((threadIdx.x & 63) == 0) {
            atomicAdd(&gsum[g0], acc);
            atomicAdd(&gcnt[g0], 64.0f);
        }
    } else if (act) {
        atomicAdd(&gsum[g], acc);
        atomicAdd(&gcnt[g], 1.0f);
    }
}

__global__ void final_k(float* __restrict__ out, const float* __restrict__ gsum,
                        const float* __restrict__ gcnt, const float* __restrict__ lb) {
    int g = blockIdx.x * blockDim.x + threadIdx.x;
    if (g < N_GRAPHS) out[g] = gsum[g] / fmaxf(gcnt[g], 1.0f) + lb[0];
}

// ---------------------------------------------------------------------------
extern "C" void kernel_launch(void* const* d_in, const int* in_sizes, int n_in,
                              void* d_out, int out_size, void* d_ws, size_t ws_size,
                              hipStream_t stream) {
    const float* x     = (const float*)d_in[0];
    const int*   eidx  = (const int*)d_in[1];   // [2, E] int32
    const int*   batch = (const int*)d_in[3];
    const float* W1 = (const float*)d_in[4];
    const float* b1 = (const float*)d_in[5];
    const float* W2 = (const float*)d_in[6];
    const float* b2 = (const float*)d_in[7];
    const float* W3 = (const float*)d_in[8];
    const float* b3 = (const float*)d_in[9];
    const float* lin_w = (const float*)d_in[10];
    const float* lin_b = (const float*)d_in[11];
    float* out = (float*)d_out;

    const int* src = eidx;
    const int* dst = eidx + N_EDGES;

    float*  ws     = (float*)d_ws;
    float*  dinv   = ws;                         // 100352 f
    int*    rowptr = (int*)(ws + 100352);        // 100352 i (needs 100001)
    int*    cbase  = rowptr + 100352;            // 512 (needs 392)
    int*    bsum   = cbase + 512;                // 1600 (needs 1564)
    int*    boff   = bsum + 1600;                // 1600
    int*    H      = boff + 1600;                // 400384
    int*    goff   = H + 400384;                 // 400384
    int2*   epack  = (int2*)(goff + 400384);     // 1.6M int2; 16B-aligned
    __half* bufH   = (__half*)(epack + N_EDGES); // 6.4M halfs (12.8 MB) gemm-out
    float*  bufF   = (float*)(bufH + 6400000);   // 6.4M f (25.6 MB) agg-out
    float*  gsum   = bufF + 6400000;             // 1024
    float*  gcnt   = gsum + 1024;                // 1024
    float*  wt     = gcnt + 1024;                // 128 (needs 64)
    float*  bc     = wt + 128;                   // 16 (needs 1)
    float*  s      = bc + 16;                    // 100352   (~56 MB total)
    int*    eC     = (int*)bufH;                 // 1.6M i, aliases bufH (dead before gemm1)

    // ---- precompute + CSR build (deterministic; zero global atomics) ----
    wtilde_k<<<5, 256, 0, stream>>>(W3, b3, lin_w, wt, bc, gsum, gcnt);
    coarse_hist_k<<<NBLK_AB, 256, 0, stream>>>(dst, H);
    scanA_k<<<NSCN, 256, 0, stream>>>(H, bsum);
    scanB_k<<<1, 1024, 0, stream>>>(bsum, boff);
    scanC_k<<<NSCN, 256, 0, stream>>>(H, boff, goff, cbase);
    coarse_scatter_k<<<NBLK_AB, 256, 0, stream>>>(src, dst, goff, eC);
    bucket_count_k<<<NCOARSE, 1024, 0, stream>>>(eC, cbase, rowptr, dinv);
    bucket_scatter_k<<<NCOARSE, 1024, 0, stream>>>(eC, cbase, rowptr, dinv, epack);

    // ---- layers 1 & 2 (relu folded into agg store) ----
    gemm_k<F_IN><<<1563, 256, 0, stream>>>(x, W1, bufH);
    agg_k<true><<<25000, 256, 0, stream>>>(rowptr, epack, dinv, bufH, b1, bufF);

    gemm_k<HDIM><<<1563, 256, 0, stream>>>(bufF, W2, bufH);
    agg_k<true><<<25000, 256, 0, stream>>>(rowptr, epack, dinv, bufH, b2, bufF);

    // ---- layer 3 collapsed to scalar aggregation + fused pool ----
    s_k<<<391, 256, 0, stream>>>(bufF, wt, s);
    agg3s_k<<<391, 256, 0, stream>>>(rowptr, epack, dinv, s, batch, bc, gsum, gcnt);
    final_k<<<(N_GRAPHS + 255) / 256, 256, 0, stream>>>(out, gsum, gcnt, lin_b);
}